// Round 1
// 1830.644 us; speedup vs baseline: 1.0810x; 1.0810x over previous
//
#include <hip/hip_runtime.h>
#include <hip/hip_bf16.h>

#define NN 200000
#define EE 600000
#define ND 32
#define EMB 128
#define NI_C 120000
#define NEGS 0.1f
#define LNEPS 1e-5f
#define CH 782   // (NN+255)/256 scan chunks

typedef short bf16x8 __attribute__((ext_vector_type(8)));
typedef float f32x4 __attribute__((ext_vector_type(4)));

__device__ __forceinline__ float leakyf(float x) { return x >= 0.0f ? x : NEGS * x; }
__device__ __forceinline__ void fma4(float4& a, float s, const float4& w) {
    a.x = fmaf(s, w.x, a.x); a.y = fmaf(s, w.y, a.y);
    a.z = fmaf(s, w.z, a.z); a.w = fmaf(s, w.w, a.w);
}
__device__ __forceinline__ float bfu2f(unsigned int u) { return __uint_as_float(u << 16); }
__device__ __forceinline__ unsigned short f2bf_rne(float x) {
    unsigned int u = __float_as_uint(x);
    u = (u + 0x7fffu + ((u >> 16) & 1u)) >> 16;
    return (unsigned short)u;
}

// ---------------- histograms: row (for deg/isq) + col (for CSR) ----------------
__global__ __launch_bounds__(256) void k_hist(const int* __restrict__ ei_nn,
                                              const int* __restrict__ ei_net,
                                              int* __restrict__ cnt_nn, int* __restrict__ cnt_net,
                                              int* __restrict__ ccol_nn, int* __restrict__ ccol_net) {
    int e = blockIdx.x * 256 + threadIdx.x;
    if (e < EE) {
        atomicAdd(&cnt_nn[ei_nn[e]], 1);            // row histogram (deg)
        atomicAdd(&cnt_net[ei_net[e]], 1);
        atomicAdd(&ccol_nn[ei_nn[EE + e]], 1);      // col histogram (CSR)
        atomicAdd(&ccol_net[ei_net[EE + e]], 1);
    }
}

__global__ __launch_bounds__(256) void k_deg(const int* __restrict__ cnt_nn,
                                             const int* __restrict__ cnt_net,
                                             float* __restrict__ isq_nn, float* __restrict__ isq_net) {
    int n = blockIdx.x * 256 + threadIdx.x;
    if (n < NN) {
        isq_nn[n]  = rsqrtf((float)(cnt_nn[n] + 1));
        isq_net[n] = rsqrtf((float)(cnt_net[n] + 1));
    }
}

// ---------------- exclusive scan (3-kernel, 200k ints) ----------------
__global__ __launch_bounds__(256) void k_scan1(const int* __restrict__ cnt,
                                               int* __restrict__ ptr, int* __restrict__ bsum) {
    __shared__ int s[256];
    int t = threadIdx.x, i = blockIdx.x * 256 + t;
    int v = (i < NN) ? cnt[i] : 0;
    s[t] = v; __syncthreads();
    for (int off = 1; off < 256; off <<= 1) {
        int u = (t >= off) ? s[t - off] : 0;
        __syncthreads();
        s[t] += u; __syncthreads();
    }
    if (i < NN) ptr[i] = s[t] - v;
    if (t == 255) bsum[blockIdx.x] = s[255];
}

__global__ __launch_bounds__(1024) void k_scan2(int* __restrict__ bsum) {
    __shared__ int s[1024];
    int t = threadIdx.x;
    int v = (t < CH) ? bsum[t] : 0;
    s[t] = v; __syncthreads();
    for (int off = 1; off < 1024; off <<= 1) {
        int u = (t >= off) ? s[t - off] : 0;
        __syncthreads();
        s[t] += u; __syncthreads();
    }
    if (t < CH) bsum[t] = s[t] - v;   // exclusive block offsets
}

__global__ __launch_bounds__(256) void k_scan3(int* __restrict__ ptr, const int* __restrict__ bsum) {
    int i = blockIdx.x * 256 + threadIdx.x;
    if (i < NN) ptr[i] += bsum[blockIdx.x];
    if (i == 0) ptr[NN] = EE;
}

// ---------------- CSR fill (both directions) ----------------
__global__ __launch_bounds__(256) void k_fill(const int* __restrict__ ei_nn, const int* __restrict__ ei_net,
                                              const int* __restrict__ ptr_nn, const int* __restrict__ ptr_net,
                                              int* __restrict__ cur_nn, int* __restrict__ cur_net,
                                              int* __restrict__ adj_nn, int* __restrict__ adj_net) {
    int e = blockIdx.x * 256 + threadIdx.x;
    if (e < EE) {
        int c1 = ei_nn[EE + e];
        int p1 = ptr_nn[c1] + atomicAdd(&cur_nn[c1], 1);
        adj_nn[p1] = ei_nn[e];
        int c2 = ei_net[EE + e];
        int p2 = ptr_net[c2] + atomicAdd(&cur_net[c2], 1);
        adj_net[p2] = ei_net[e];
    }
}

// ---------------- encoder: h0 = leaky(leaky(x@W1+b1)@W2+b2) ----------------
__global__ __launch_bounds__(256) void k_encoder(const float* __restrict__ x,
                                                 const float* __restrict__ w1, const float* __restrict__ b1,
                                                 const float* __restrict__ w2, const float* __restrict__ b2,
                                                 float* __restrict__ H, float* __restrict__ out) {
    __shared__ float4 xs[512];
    __shared__ __align__(16) __hip_bfloat16 hs[64 * 256];
    int tid = threadIdx.x;
    int n0 = blockIdx.x * 64;

    const float4* xg = (const float4*)(x + (size_t)n0 * ND);
    for (int p = tid; p < 512; p += 256) xs[p] = xg[p];
    __syncthreads();

    {
        float w[32];
#pragma unroll
        for (int k = 0; k < 32; k++) w[k] = w1[k * 256 + tid];
        float bj = b1[tid];
        for (int n = 0; n < 64; n++) {
            float acc = bj;
#pragma unroll
            for (int k4 = 0; k4 < 8; k4++) {
                float4 xv = xs[n * 8 + k4];
                acc = fmaf(xv.x, w[4 * k4 + 0], acc);
                acc = fmaf(xv.y, w[4 * k4 + 1], acc);
                acc = fmaf(xv.z, w[4 * k4 + 2], acc);
                acc = fmaf(xv.w, w[4 * k4 + 3], acc);
            }
            hs[n * 256 + tid] = __float2bfloat16(leakyf(acc));
        }
    }
    __syncthreads();

    int tx = tid & 31, ty = tid >> 5;
    float4 bias = ((const float4*)b2)[tx];
    float4 acc[8];
#pragma unroll
    for (int i = 0; i < 8; i++) acc[i] = bias;

    const float4* w2g = (const float4*)w2;
    const unsigned short* hsu = (const unsigned short*)hs;
    for (int k4 = 0; k4 < 64; k4++) {
        float4 w0 = w2g[(4 * k4 + 0) * 32 + tx];
        float4 wv1 = w2g[(4 * k4 + 1) * 32 + tx];
        float4 wv2 = w2g[(4 * k4 + 2) * 32 + tx];
        float4 wv3 = w2g[(4 * k4 + 3) * 32 + tx];
#pragma unroll
        for (int i = 0; i < 8; i++) {
            int n = ty * 8 + i;
            uint2 hv = *(const uint2*)(hsu + n * 256 + 4 * k4);
            float a0 = bfu2f(hv.x & 0xffffu);
            float a1 = bfu2f(hv.x >> 16);
            float a2 = bfu2f(hv.y & 0xffffu);
            float a3 = bfu2f(hv.y >> 16);
            fma4(acc[i], a0, w0); fma4(acc[i], a1, wv1);
            fma4(acc[i], a2, wv2); fma4(acc[i], a3, wv3);
        }
    }
#pragma unroll
    for (int i = 0; i < 8; i++) {
        int n = n0 + ty * 8 + i;
        float4 v;
        v.x = leakyf(acc[i].x); v.y = leakyf(acc[i].y);
        v.z = leakyf(acc[i].z); v.w = leakyf(acc[i].w);
        ((float4*)H)[(size_t)n * 32 + tx] = v;
        if (n < NI_C) ((float4*)out)[(size_t)n * 128 + tx] = v;
    }
}

// ---------------- XL = A @ W + b via split-bf16 MFMA (near-fp32 accuracy) ----------------
// Block: 64 rows x 128 cols, 4 waves (16 rows each), 2 col-halves of 64.
// A ~ A_hi + A_lo (bf16 each); W ~ W_hi + W_lo; 3-term mfma: hh + lh + hl.
// k-slot ordering packed identically into A and B operands -> invariant to HW k-permutation.
// C/D layout (m89-verified): col = lane&15, row = (lane>>4)*4 + reg.
__global__ __launch_bounds__(256) void k_matmul_mfma(const float* __restrict__ A,
                                                     const float* __restrict__ W,
                                                     const float* __restrict__ bias,
                                                     float* __restrict__ out) {
    __shared__ unsigned short wt_hi[64][136];   // W^T, pad 8 -> 272B rows, 2-way max aliasing
    __shared__ unsigned short wt_lo[64][136];
    int tid = threadIdx.x;
    int lane = tid & 63, wv = tid >> 6;
    int g = lane >> 4, r = lane & 15;
    const float* arow = A + ((size_t)blockIdx.x * 64 + wv * 16 + r) * 128;

    // Per-lane A fragments: 8 contiguous fp32 at k = kc*32 + g*8, split hi/lo in-register.
    bf16x8 ahi[4], alo[4];
#pragma unroll
    for (int kc = 0; kc < 4; kc++) {
        int kk = kc * 32 + g * 8;
        float4 v0 = *(const float4*)(arow + kk);
        float4 v1 = *(const float4*)(arow + kk + 4);
        float av[8] = {v0.x, v0.y, v0.z, v0.w, v1.x, v1.y, v1.z, v1.w};
#pragma unroll
        for (int i = 0; i < 8; i++) {
            unsigned short h = f2bf_rne(av[i]);
            float hf = __uint_as_float((unsigned int)h << 16);
            unsigned short l = f2bf_rne(av[i] - hf);
            ahi[kc][i] = (short)h;
            alo[kc][i] = (short)l;
        }
    }

    int sc = tid >> 2;            // staging col within half (0..63)
    int sk0 = (tid & 3) * 32;     // staging k base
    for (int h = 0; h < 2; h++) {
        if (h) __syncthreads();   // previous half's LDS reads done before restage
        const float* wp = W + (size_t)h * 64 + sc;
        for (int j = 0; j < 32; j += 4) {
            float b0 = wp[(size_t)(sk0 + j + 0) * 128];
            float b1 = wp[(size_t)(sk0 + j + 1) * 128];
            float b2 = wp[(size_t)(sk0 + j + 2) * 128];
            float b3 = wp[(size_t)(sk0 + j + 3) * 128];
            ushort4 hh, ll;
            hh.x = f2bf_rne(b0); ll.x = f2bf_rne(b0 - __uint_as_float((unsigned int)hh.x << 16));
            hh.y = f2bf_rne(b1); ll.y = f2bf_rne(b1 - __uint_as_float((unsigned int)hh.y << 16));
            hh.z = f2bf_rne(b2); ll.z = f2bf_rne(b2 - __uint_as_float((unsigned int)hh.z << 16));
            hh.w = f2bf_rne(b3); ll.w = f2bf_rne(b3 - __uint_as_float((unsigned int)hh.w << 16));
            *(ushort4*)&wt_hi[sc][sk0 + j] = hh;
            *(ushort4*)&wt_lo[sc][sk0 + j] = ll;
        }
        __syncthreads();

        f32x4 acc[4];
#pragma unroll
        for (int t = 0; t < 4; t++) acc[t] = (f32x4){0.0f, 0.0f, 0.0f, 0.0f};
#pragma unroll
        for (int kc = 0; kc < 4; kc++) {
            int kk = kc * 32 + g * 8;
#pragma unroll
            for (int t = 0; t < 4; t++) {
                bf16x8 bh = *(const bf16x8*)&wt_hi[t * 16 + r][kk];
                bf16x8 bl = *(const bf16x8*)&wt_lo[t * 16 + r][kk];
                acc[t] = __builtin_amdgcn_mfma_f32_16x16x32_bf16(ahi[kc], bh, acc[t], 0, 0, 0);
                acc[t] = __builtin_amdgcn_mfma_f32_16x16x32_bf16(alo[kc], bh, acc[t], 0, 0, 0);
                acc[t] = __builtin_amdgcn_mfma_f32_16x16x32_bf16(ahi[kc], bl, acc[t], 0, 0, 0);
            }
        }

        size_t orow = (size_t)blockIdx.x * 64 + wv * 16 + g * 4;
#pragma unroll
        for (int t = 0; t < 4; t++) {
            int cc = h * 64 + t * 16 + r;
            float bv = bias[cc];
#pragma unroll
            for (int q = 0; q < 4; q++)
                out[(orow + q) * 128 + cc] = acc[t][q] + bv;
        }
    }
}

// ---------------- fused gather 1: AGG = isq[n]*sum(isq[r]*relu(XL[r])) + relu(XL[n]+root)*isq[n]^2
__global__ __launch_bounds__(256) void k_gather1(const float* __restrict__ XL,
                                                 float* __restrict__ AGG,
                                                 const int* __restrict__ adj, const int* __restrict__ ptr,
                                                 const float* __restrict__ isq,
                                                 const float* __restrict__ root) {
    int tid = threadIdx.x;
    int lane = tid & 63;
    int n = blockIdx.x * 4 + (tid >> 6);
    int s = ptr[n], e = ptr[n + 1];
    float a0 = 0.0f, a1 = 0.0f;
    for (int i = s; i < e; i++) {
        int r = adj[i];
        float w = isq[r];
        float2 v = ((const float2*)XL)[(size_t)r * 64 + lane];
        a0 = fmaf(w, fmaxf(v.x, 0.0f), a0);
        a1 = fmaf(w, fmaxf(v.y, 0.0f), a1);
    }
    float iq = isq[n];
    float id = iq * iq;
    float2 xv = ((const float2*)XL)[(size_t)n * 64 + lane];
    float2 rv = ((const float2*)root)[lane];
    float2 o;
    o.x = iq * a0 + fmaxf(xv.x + rv.x, 0.0f) * id;
    o.y = iq * a1 + fmaxf(xv.y + rv.y, 0.0f) * id;
    ((float2*)AGG)[(size_t)n * 64 + lane] = o;
}

// ---------------- fused gather 2: gather + self + LN + leaky + residual + out slice
__global__ __launch_bounds__(256) void k_gather2(const float* __restrict__ XL,
                                                 float* __restrict__ H,
                                                 const int* __restrict__ adj, const int* __restrict__ ptr,
                                                 const float* __restrict__ isq,
                                                 const float* __restrict__ root,
                                                 const float* __restrict__ g, const float* __restrict__ b,
                                                 float* __restrict__ out, int layer_off) {
    int tid = threadIdx.x;
    int lane = tid & 63;
    int n = blockIdx.x * 4 + (tid >> 6);
    int s = ptr[n], e = ptr[n + 1];
    float a0 = 0.0f, a1 = 0.0f;
    for (int i = s; i < e; i++) {
        int r = adj[i];
        float w = isq[r];
        float2 v = ((const float2*)XL)[(size_t)r * 64 + lane];
        a0 = fmaf(w, fmaxf(v.x, 0.0f), a0);
        a1 = fmaf(w, fmaxf(v.y, 0.0f), a1);
    }
    float iq = isq[n];
    float id = iq * iq;
    float2 xv = ((const float2*)XL)[(size_t)n * 64 + lane];
    float2 rv = ((const float2*)root)[lane];
    float t0 = iq * a0 + fmaxf(xv.x + rv.x, 0.0f) * id;
    float t1 = iq * a1 + fmaxf(xv.y + rv.y, 0.0f) * id;

    float sm = t0 + t1;
#pragma unroll
    for (int off = 32; off; off >>= 1) sm += __shfl_xor(sm, off, 64);
    float mu = sm * (1.0f / 128.0f);
    float d0 = t0 - mu, d1 = t1 - mu;
    float q = d0 * d0 + d1 * d1;
#pragma unroll
    for (int off = 32; off; off >>= 1) q += __shfl_xor(q, off, 64);
    float rs = rsqrtf(q * (1.0f / 128.0f) + LNEPS);

    float2 gv = ((const float2*)g)[lane];
    float2 bv = ((const float2*)b)[lane];
    float y0 = leakyf(d0 * rs * gv.x + bv.x);
    float y1 = leakyf(d1 * rs * gv.y + bv.y);

    float2* h2 = (float2*)H + (size_t)n * 64 + lane;
    float2 hv = *h2;
    float2 o2; o2.x = y0 + hv.x; o2.y = y1 + hv.y;
    *h2 = o2;
    if (n < NI_C) ((float2*)out)[(size_t)n * 256 + (layer_off >> 1) + lane] = o2;
}

extern "C" void kernel_launch(void* const* d_in, const int* in_sizes, int n_in,
                              void* d_out, int out_size, void* d_ws, size_t ws_size,
                              hipStream_t stream) {
    const float* x         = (const float*)d_in[0];
    const float* enc_w1    = (const float*)d_in[1];
    const float* enc_b1    = (const float*)d_in[2];
    const float* enc_w2    = (const float*)d_in[3];
    const float* enc_b2    = (const float*)d_in[4];
    const float* conv_w    = (const float*)d_in[5];
    const float* conv_b    = (const float*)d_in[6];
    const float* conv_root = (const float*)d_in[7];
    const float* reconv_w    = (const float*)d_in[8];
    const float* reconv_b    = (const float*)d_in[9];
    const float* reconv_root = (const float*)d_in[10];
    const float* ln_g = (const float*)d_in[11];
    const float* ln_b = (const float*)d_in[12];
    const int* ei_nn  = (const int*)d_in[13];
    const int* ei_net = (const int*)d_in[14];
    float* out = (float*)d_out;

    char* ws = (char*)d_ws;
    size_t off = 0;
    const size_t big = (size_t)NN * EMB * sizeof(float);  // 102.4 MB
    float* H  = (float*)(ws + off); off += big;
    float* XL = (float*)(ws + off); off += big;
    float* HC = (float*)(ws + off); off += big;
    float* isq_nn  = (float*)(ws + off); off += (size_t)NN * 4;
    float* isq_net = (float*)(ws + off); off += (size_t)NN * 4;
    // histogram block (contiguous for single memset): cnt_nn, cnt_net, ccol_nn, ccol_net
    int* cnt_nn  = (int*)(ws + off); off += (size_t)NN * 4;   // reused as cur_nn after k_deg
    int* cnt_net = (int*)(ws + off); off += (size_t)NN * 4;   // reused as cur_net
    int* ccol_nn  = (int*)(ws + off); off += (size_t)NN * 4;
    int* ccol_net = (int*)(ws + off); off += (size_t)NN * 4;
    int* ptr_nn  = (int*)(ws + off); off += (size_t)(NN + 1) * 4;
    int* ptr_net = (int*)(ws + off); off += (size_t)(NN + 1) * 4;
    int* adj_nn  = (int*)(ws + off); off += (size_t)EE * 4;
    int* adj_net = (int*)(ws + off); off += (size_t)EE * 4;
    int* bsum_nn  = (int*)(ws + off); off += (size_t)1024 * 4;
    int* bsum_net = (int*)(ws + off); off += (size_t)1024 * 4;

    // ---- CSR + degree build (once per launch, reused by all 3 layers) ----
    hipMemsetAsync(cnt_nn, 0, (size_t)NN * 4 * 4, stream);  // all 4 histograms
    k_hist<<<(EE + 255) / 256, 256, 0, stream>>>(ei_nn, ei_net, cnt_nn, cnt_net, ccol_nn, ccol_net);
    k_deg<<<(NN + 255) / 256, 256, 0, stream>>>(cnt_nn, cnt_net, isq_nn, isq_net);
    k_scan1<<<CH, 256, 0, stream>>>(ccol_nn, ptr_nn, bsum_nn);
    k_scan1<<<CH, 256, 0, stream>>>(ccol_net, ptr_net, bsum_net);
    k_scan2<<<1, 1024, 0, stream>>>(bsum_nn);
    k_scan2<<<1, 1024, 0, stream>>>(bsum_net);
    k_scan3<<<CH, 256, 0, stream>>>(ptr_nn, bsum_nn);
    k_scan3<<<CH, 256, 0, stream>>>(ptr_net, bsum_net);
    hipMemsetAsync(cnt_nn, 0, (size_t)NN * 4 * 2, stream);  // zero fill cursors (reuse cnt)
    k_fill<<<(EE + 255) / 256, 256, 0, stream>>>(ei_nn, ei_net, ptr_nn, ptr_net,
                                                 cnt_nn, cnt_net, adj_nn, adj_net);

    // ---- encoder -> H, out[:,0:128] ----
    k_encoder<<<NN / 64, 256, 0, stream>>>(x, enc_w1, enc_b1, enc_w2, enc_b2, H, out);

    for (int l = 0; l < 3; l++) {
        // GCN 1 (node_net edges)
        k_matmul_mfma<<<NN / 64, 256, 0, stream>>>(H, conv_w + (size_t)l * EMB * EMB, conv_b + l * EMB, XL);
        k_gather1<<<NN / 4, 256, 0, stream>>>(XL, HC, adj_nn, ptr_nn, isq_nn, conv_root + l * EMB);

        // GCN 2 (net_node edges) + LN + leaky + residual
        k_matmul_mfma<<<NN / 64, 256, 0, stream>>>(HC, reconv_w + (size_t)l * EMB * EMB, reconv_b + l * EMB, XL);
        k_gather2<<<NN / 4, 256, 0, stream>>>(XL, H, adj_net, ptr_net, isq_net, reconv_root + l * EMB,
                                              ln_g + l * EMB, ln_b + l * EMB, out, (l + 1) * EMB);
    }
}

// Round 8
// 1702.762 us; speedup vs baseline: 1.1622x; 1.0751x over previous
//
#include <hip/hip_runtime.h>
#include <hip/hip_bf16.h>

#define NN 200000
#define EE 600000
#define ND 32
#define EMB 128
#define NI_C 120000
#define NEGS 0.1f
#define LNEPS 1e-5f
#define CH 782   // (NN+255)/256 scan chunks

typedef short bf16x8 __attribute__((ext_vector_type(8)));
typedef float f32x4 __attribute__((ext_vector_type(4)));

__device__ __forceinline__ float leakyf(float x) { return x >= 0.0f ? x : NEGS * x; }
__device__ __forceinline__ void fma4(float4& a, float s, const float4& w) {
    a.x = fmaf(s, w.x, a.x); a.y = fmaf(s, w.y, a.y);
    a.z = fmaf(s, w.z, a.z); a.w = fmaf(s, w.w, a.w);
}
__device__ __forceinline__ float bfu2f(unsigned int u) { return __uint_as_float(u << 16); }
__device__ __forceinline__ unsigned short f2bf_rne(float x) {
    unsigned int u = __float_as_uint(x);
    u = (u + 0x7fffu + ((u >> 16) & 1u)) >> 16;
    return (unsigned short)u;
}

// ---------------- histograms: row (for deg/isq) + col (for CSR) ----------------
__global__ __launch_bounds__(256) void k_hist(const int* __restrict__ ei_nn,
                                              const int* __restrict__ ei_net,
                                              int* __restrict__ cnt_nn, int* __restrict__ cnt_net,
                                              int* __restrict__ ccol_nn, int* __restrict__ ccol_net) {
    int e = blockIdx.x * 256 + threadIdx.x;
    if (e < EE) {
        atomicAdd(&cnt_nn[ei_nn[e]], 1);            // row histogram (deg)
        atomicAdd(&cnt_net[ei_net[e]], 1);
        atomicAdd(&ccol_nn[ei_nn[EE + e]], 1);      // col histogram (CSR)
        atomicAdd(&ccol_net[ei_net[EE + e]], 1);
    }
}

__global__ __launch_bounds__(256) void k_deg(const int* __restrict__ cnt_nn,
                                             const int* __restrict__ cnt_net,
                                             float* __restrict__ isq_nn, float* __restrict__ isq_net) {
    int n = blockIdx.x * 256 + threadIdx.x;
    if (n < NN) {
        isq_nn[n]  = rsqrtf((float)(cnt_nn[n] + 1));
        isq_net[n] = rsqrtf((float)(cnt_net[n] + 1));
    }
}

// ---------------- exclusive scan (3-kernel, 200k ints) ----------------
__global__ __launch_bounds__(256) void k_scan1(const int* __restrict__ cnt,
                                               int* __restrict__ ptr, int* __restrict__ bsum) {
    __shared__ int s[256];
    int t = threadIdx.x, i = blockIdx.x * 256 + t;
    int v = (i < NN) ? cnt[i] : 0;
    s[t] = v; __syncthreads();
    for (int off = 1; off < 256; off <<= 1) {
        int u = (t >= off) ? s[t - off] : 0;
        __syncthreads();
        s[t] += u; __syncthreads();
    }
    if (i < NN) ptr[i] = s[t] - v;
    if (t == 255) bsum[blockIdx.x] = s[255];
}

__global__ __launch_bounds__(1024) void k_scan2(int* __restrict__ bsum) {
    __shared__ int s[1024];
    int t = threadIdx.x;
    int v = (t < CH) ? bsum[t] : 0;
    s[t] = v; __syncthreads();
    for (int off = 1; off < 1024; off <<= 1) {
        int u = (t >= off) ? s[t - off] : 0;
        __syncthreads();
        s[t] += u; __syncthreads();
    }
    if (t < CH) bsum[t] = s[t] - v;   // exclusive block offsets
}

__global__ __launch_bounds__(256) void k_scan3(int* __restrict__ ptr, const int* __restrict__ bsum) {
    int i = blockIdx.x * 256 + threadIdx.x;
    if (i < NN) ptr[i] += bsum[blockIdx.x];
    if (i == 0) ptr[NN] = EE;
}

// ---------------- CSR fill (both directions) ----------------
__global__ __launch_bounds__(256) void k_fill(const int* __restrict__ ei_nn, const int* __restrict__ ei_net,
                                              const int* __restrict__ ptr_nn, const int* __restrict__ ptr_net,
                                              int* __restrict__ cur_nn, int* __restrict__ cur_net,
                                              int* __restrict__ adj_nn, int* __restrict__ adj_net) {
    int e = blockIdx.x * 256 + threadIdx.x;
    if (e < EE) {
        int c1 = ei_nn[EE + e];
        int p1 = ptr_nn[c1] + atomicAdd(&cur_nn[c1], 1);
        adj_nn[p1] = ei_nn[e];
        int c2 = ei_net[EE + e];
        int p2 = ptr_net[c2] + atomicAdd(&cur_net[c2], 1);
        adj_net[p2] = ei_net[e];
    }
}

// ---------------- encoder: h0 = leaky(leaky(x@W1+b1)@W2+b2) ----------------
// R0-verified VALU path, verbatim (encoder-MFMA line parked after R3/R4/R7 failures).
__global__ __launch_bounds__(256) void k_encoder(const float* __restrict__ x,
                                                 const float* __restrict__ w1, const float* __restrict__ b1,
                                                 const float* __restrict__ w2, const float* __restrict__ b2,
                                                 float* __restrict__ H, float* __restrict__ out) {
    __shared__ float4 xs[512];
    __shared__ __align__(16) __hip_bfloat16 hs[64 * 256];
    int tid = threadIdx.x;
    int n0 = blockIdx.x * 64;

    const float4* xg = (const float4*)(x + (size_t)n0 * ND);
    for (int p = tid; p < 512; p += 256) xs[p] = xg[p];
    __syncthreads();

    {
        float w[32];
#pragma unroll
        for (int k = 0; k < 32; k++) w[k] = w1[k * 256 + tid];
        float bj = b1[tid];
        for (int n = 0; n < 64; n++) {
            float acc = bj;
#pragma unroll
            for (int k4 = 0; k4 < 8; k4++) {
                float4 xv = xs[n * 8 + k4];
                acc = fmaf(xv.x, w[4 * k4 + 0], acc);
                acc = fmaf(xv.y, w[4 * k4 + 1], acc);
                acc = fmaf(xv.z, w[4 * k4 + 2], acc);
                acc = fmaf(xv.w, w[4 * k4 + 3], acc);
            }
            hs[n * 256 + tid] = __float2bfloat16(leakyf(acc));
        }
    }
    __syncthreads();

    int tx = tid & 31, ty = tid >> 5;
    float4 bias = ((const float4*)b2)[tx];
    float4 acc[8];
#pragma unroll
    for (int i = 0; i < 8; i++) acc[i] = bias;

    const float4* w2g = (const float4*)w2;
    const unsigned short* hsu = (const unsigned short*)hs;
    for (int k4 = 0; k4 < 64; k4++) {
        float4 w0 = w2g[(4 * k4 + 0) * 32 + tx];
        float4 wv1 = w2g[(4 * k4 + 1) * 32 + tx];
        float4 wv2 = w2g[(4 * k4 + 2) * 32 + tx];
        float4 wv3 = w2g[(4 * k4 + 3) * 32 + tx];
#pragma unroll
        for (int i = 0; i < 8; i++) {
            int n = ty * 8 + i;
            uint2 hv = *(const uint2*)(hsu + n * 256 + 4 * k4);
            float a0 = bfu2f(hv.x & 0xffffu);
            float a1 = bfu2f(hv.x >> 16);
            float a2 = bfu2f(hv.y & 0xffffu);
            float a3 = bfu2f(hv.y >> 16);
            fma4(acc[i], a0, w0); fma4(acc[i], a1, wv1);
            fma4(acc[i], a2, wv2); fma4(acc[i], a3, wv3);
        }
    }
#pragma unroll
    for (int i = 0; i < 8; i++) {
        int n = n0 + ty * 8 + i;
        float4 v;
        v.x = leakyf(acc[i].x); v.y = leakyf(acc[i].y);
        v.z = leakyf(acc[i].z); v.w = leakyf(acc[i].w);
        ((float4*)H)[(size_t)n * 32 + tx] = v;
        if (n < NI_C) ((float4*)out)[(size_t)n * 128 + tx] = v;
    }
}

// ---------------- XL(bf16) = A @ W + b via split-bf16 MFMA (near-fp32 accuracy) ----------------
// Epilogue now rounds to bf16: halves XL write traffic and downstream gather reads.
__global__ __launch_bounds__(256) void k_matmul_mfma(const float* __restrict__ A,
                                                     const float* __restrict__ W,
                                                     const float* __restrict__ bias,
                                                     unsigned short* __restrict__ out) {
    __shared__ unsigned short wt_hi[64][136];   // W^T, pad 8 -> 272B rows, 2-way max aliasing
    __shared__ unsigned short wt_lo[64][136];
    int tid = threadIdx.x;
    int lane = tid & 63, wv = tid >> 6;
    int g = lane >> 4, r = lane & 15;
    const float* arow = A + ((size_t)blockIdx.x * 64 + wv * 16 + r) * 128;

    // Per-lane A fragments: 8 contiguous fp32 at k = kc*32 + g*8, split hi/lo in-register.
    bf16x8 ahi[4], alo[4];
#pragma unroll
    for (int kc = 0; kc < 4; kc++) {
        int kk = kc * 32 + g * 8;
        float4 v0 = *(const float4*)(arow + kk);
        float4 v1 = *(const float4*)(arow + kk + 4);
        float av[8] = {v0.x, v0.y, v0.z, v0.w, v1.x, v1.y, v1.z, v1.w};
#pragma unroll
        for (int i = 0; i < 8; i++) {
            unsigned short h = f2bf_rne(av[i]);
            float hf = __uint_as_float((unsigned int)h << 16);
            unsigned short l = f2bf_rne(av[i] - hf);
            ahi[kc][i] = (short)h;
            alo[kc][i] = (short)l;
        }
    }

    int sc = tid >> 2;            // staging col within half (0..63)
    int sk0 = (tid & 3) * 32;     // staging k base
    for (int h = 0; h < 2; h++) {
        if (h) __syncthreads();   // previous half's LDS reads done before restage
        const float* wp = W + (size_t)h * 64 + sc;
        for (int j = 0; j < 32; j += 4) {
            float b0 = wp[(size_t)(sk0 + j + 0) * 128];
            float b1 = wp[(size_t)(sk0 + j + 1) * 128];
            float b2 = wp[(size_t)(sk0 + j + 2) * 128];
            float b3 = wp[(size_t)(sk0 + j + 3) * 128];
            ushort4 hh, ll;
            hh.x = f2bf_rne(b0); ll.x = f2bf_rne(b0 - __uint_as_float((unsigned int)hh.x << 16));
            hh.y = f2bf_rne(b1); ll.y = f2bf_rne(b1 - __uint_as_float((unsigned int)hh.y << 16));
            hh.z = f2bf_rne(b2); ll.z = f2bf_rne(b2 - __uint_as_float((unsigned int)hh.z << 16));
            hh.w = f2bf_rne(b3); ll.w = f2bf_rne(b3 - __uint_as_float((unsigned int)hh.w << 16));
            *(ushort4*)&wt_hi[sc][sk0 + j] = hh;
            *(ushort4*)&wt_lo[sc][sk0 + j] = ll;
        }
        __syncthreads();

        f32x4 acc[4];
#pragma unroll
        for (int t = 0; t < 4; t++) acc[t] = (f32x4){0.0f, 0.0f, 0.0f, 0.0f};
#pragma unroll
        for (int kc = 0; kc < 4; kc++) {
            int kk = kc * 32 + g * 8;
#pragma unroll
            for (int t = 0; t < 4; t++) {
                bf16x8 bh = *(const bf16x8*)&wt_hi[t * 16 + r][kk];
                bf16x8 bl = *(const bf16x8*)&wt_lo[t * 16 + r][kk];
                acc[t] = __builtin_amdgcn_mfma_f32_16x16x32_bf16(ahi[kc], bh, acc[t], 0, 0, 0);
                acc[t] = __builtin_amdgcn_mfma_f32_16x16x32_bf16(alo[kc], bh, acc[t], 0, 0, 0);
                acc[t] = __builtin_amdgcn_mfma_f32_16x16x32_bf16(ahi[kc], bl, acc[t], 0, 0, 0);
            }
        }

        size_t orow = (size_t)blockIdx.x * 64 + wv * 16 + g * 4;
#pragma unroll
        for (int t = 0; t < 4; t++) {
            int cc = h * 64 + t * 16 + r;
            float bv = bias[cc];
#pragma unroll
            for (int q = 0; q < 4; q++)
                out[(orow + q) * 128 + cc] = f2bf_rne(acc[t][q] + bv);
        }
    }
}

// ---------------- fused gather 1 (bf16 XL): AGG = isq[n]*sum(isq[r]*relu(XL[r])) + relu(XL[n]+root)*isq[n]^2
__global__ __launch_bounds__(256) void k_gather1(const unsigned short* __restrict__ XLb,
                                                 float* __restrict__ AGG,
                                                 const int* __restrict__ adj, const int* __restrict__ ptr,
                                                 const float* __restrict__ isq,
                                                 const float* __restrict__ root) {
    const unsigned int* XLu = (const unsigned int*)XLb;
    int tid = threadIdx.x;
    int lane = tid & 63;
    int n = blockIdx.x * 4 + (tid >> 6);
    int s = ptr[n], e = ptr[n + 1];
    float a0 = 0.0f, a1 = 0.0f;
    for (int i = s; i < e; i++) {
        int r = adj[i];
        float w = isq[r];
        unsigned int u = XLu[(size_t)r * 64 + lane];
        a0 = fmaf(w, fmaxf(__uint_as_float(u << 16), 0.0f), a0);
        a1 = fmaf(w, fmaxf(__uint_as_float(u & 0xffff0000u), 0.0f), a1);
    }
    float iq = isq[n];
    float id = iq * iq;
    unsigned int su = XLu[(size_t)n * 64 + lane];
    float x0 = __uint_as_float(su << 16);
    float x1 = __uint_as_float(su & 0xffff0000u);
    float2 rv = ((const float2*)root)[lane];
    float2 o;
    o.x = iq * a0 + fmaxf(x0 + rv.x, 0.0f) * id;
    o.y = iq * a1 + fmaxf(x1 + rv.y, 0.0f) * id;
    ((float2*)AGG)[(size_t)n * 64 + lane] = o;
}

// ---------------- fused gather 2 (bf16 XL): gather + self + LN + leaky + residual + out slice
__global__ __launch_bounds__(256) void k_gather2(const unsigned short* __restrict__ XLb,
                                                 float* __restrict__ H,
                                                 const int* __restrict__ adj, const int* __restrict__ ptr,
                                                 const float* __restrict__ isq,
                                                 const float* __restrict__ root,
                                                 const float* __restrict__ g, const float* __restrict__ b,
                                                 float* __restrict__ out, int layer_off) {
    const unsigned int* XLu = (const unsigned int*)XLb;
    int tid = threadIdx.x;
    int lane = tid & 63;
    int n = blockIdx.x * 4 + (tid >> 6);
    int s = ptr[n], e = ptr[n + 1];
    float a0 = 0.0f, a1 = 0.0f;
    for (int i = s; i < e; i++) {
        int r = adj[i];
        float w = isq[r];
        unsigned int u = XLu[(size_t)r * 64 + lane];
        a0 = fmaf(w, fmaxf(__uint_as_float(u << 16), 0.0f), a0);
        a1 = fmaf(w, fmaxf(__uint_as_float(u & 0xffff0000u), 0.0f), a1);
    }
    float iq = isq[n];
    float id = iq * iq;
    unsigned int su = XLu[(size_t)n * 64 + lane];
    float x0 = __uint_as_float(su << 16);
    float x1 = __uint_as_float(su & 0xffff0000u);
    float2 rv = ((const float2*)root)[lane];
    float t0 = iq * a0 + fmaxf(x0 + rv.x, 0.0f) * id;
    float t1 = iq * a1 + fmaxf(x1 + rv.y, 0.0f) * id;

    float sm = t0 + t1;
#pragma unroll
    for (int off = 32; off; off >>= 1) sm += __shfl_xor(sm, off, 64);
    float mu = sm * (1.0f / 128.0f);
    float d0 = t0 - mu, d1 = t1 - mu;
    float q = d0 * d0 + d1 * d1;
#pragma unroll
    for (int off = 32; off; off >>= 1) q += __shfl_xor(q, off, 64);
    float rs = rsqrtf(q * (1.0f / 128.0f) + LNEPS);

    float2 gv = ((const float2*)g)[lane];
    float2 bv = ((const float2*)b)[lane];
    float y0 = leakyf(d0 * rs * gv.x + bv.x);
    float y1 = leakyf(d1 * rs * gv.y + bv.y);

    float2* h2 = (float2*)H + (size_t)n * 64 + lane;
    float2 hv = *h2;
    float2 o2; o2.x = y0 + hv.x; o2.y = y1 + hv.y;
    *h2 = o2;
    if (n < NI_C) ((float2*)out)[(size_t)n * 256 + (layer_off >> 1) + lane] = o2;
}

extern "C" void kernel_launch(void* const* d_in, const int* in_sizes, int n_in,
                              void* d_out, int out_size, void* d_ws, size_t ws_size,
                              hipStream_t stream) {
    const float* x         = (const float*)d_in[0];
    const float* enc_w1    = (const float*)d_in[1];
    const float* enc_b1    = (const float*)d_in[2];
    const float* enc_w2    = (const float*)d_in[3];
    const float* enc_b2    = (const float*)d_in[4];
    const float* conv_w    = (const float*)d_in[5];
    const float* conv_b    = (const float*)d_in[6];
    const float* conv_root = (const float*)d_in[7];
    const float* reconv_w    = (const float*)d_in[8];
    const float* reconv_b    = (const float*)d_in[9];
    const float* reconv_root = (const float*)d_in[10];
    const float* ln_g = (const float*)d_in[11];
    const float* ln_b = (const float*)d_in[12];
    const int* ei_nn  = (const int*)d_in[13];
    const int* ei_net = (const int*)d_in[14];
    float* out = (float*)d_out;

    char* ws = (char*)d_ws;
    size_t off = 0;
    const size_t big = (size_t)NN * EMB * sizeof(float);  // 102.4 MB
    float* H  = (float*)(ws + off); off += big;
    unsigned short* XL = (unsigned short*)(ws + off); off += big;  // bf16, half used
    float* HC = (float*)(ws + off); off += big;
    float* isq_nn  = (float*)(ws + off); off += (size_t)NN * 4;
    float* isq_net = (float*)(ws + off); off += (size_t)NN * 4;
    // histogram block (contiguous for single memset): cnt_nn, cnt_net, ccol_nn, ccol_net
    int* cnt_nn  = (int*)(ws + off); off += (size_t)NN * 4;   // reused as cur_nn after k_deg
    int* cnt_net = (int*)(ws + off); off += (size_t)NN * 4;   // reused as cur_net
    int* ccol_nn  = (int*)(ws + off); off += (size_t)NN * 4;
    int* ccol_net = (int*)(ws + off); off += (size_t)NN * 4;
    int* ptr_nn  = (int*)(ws + off); off += (size_t)(NN + 1) * 4;
    int* ptr_net = (int*)(ws + off); off += (size_t)(NN + 1) * 4;
    int* adj_nn  = (int*)(ws + off); off += (size_t)EE * 4;
    int* adj_net = (int*)(ws + off); off += (size_t)EE * 4;
    int* bsum_nn  = (int*)(ws + off); off += (size_t)1024 * 4;
    int* bsum_net = (int*)(ws + off); off += (size_t)1024 * 4;

    // ---- CSR + degree build (once per launch, reused by all 3 layers) ----
    hipMemsetAsync(cnt_nn, 0, (size_t)NN * 4 * 4, stream);  // all 4 histograms
    k_hist<<<(EE + 255) / 256, 256, 0, stream>>>(ei_nn, ei_net, cnt_nn, cnt_net, ccol_nn, ccol_net);
    k_deg<<<(NN + 255) / 256, 256, 0, stream>>>(cnt_nn, cnt_net, isq_nn, isq_net);
    k_scan1<<<CH, 256, 0, stream>>>(ccol_nn, ptr_nn, bsum_nn);
    k_scan1<<<CH, 256, 0, stream>>>(ccol_net, ptr_net, bsum_net);
    k_scan2<<<1, 1024, 0, stream>>>(bsum_nn);
    k_scan2<<<1, 1024, 0, stream>>>(bsum_net);
    k_scan3<<<CH, 256, 0, stream>>>(ptr_nn, bsum_nn);
    k_scan3<<<CH, 256, 0, stream>>>(ptr_net, bsum_net);
    hipMemsetAsync(cnt_nn, 0, (size_t)NN * 4 * 2, stream);  // zero fill cursors (reuse cnt)
    k_fill<<<(EE + 255) / 256, 256, 0, stream>>>(ei_nn, ei_net, ptr_nn, ptr_net,
                                                 cnt_nn, cnt_net, adj_nn, adj_net);

    // ---- encoder -> H, out[:,0:128] ----
    k_encoder<<<NN / 64, 256, 0, stream>>>(x, enc_w1, enc_b1, enc_w2, enc_b2, H, out);

    for (int l = 0; l < 3; l++) {
        // GCN 1 (node_net edges)
        k_matmul_mfma<<<NN / 64, 256, 0, stream>>>(H, conv_w + (size_t)l * EMB * EMB, conv_b + l * EMB, XL);
        k_gather1<<<NN / 4, 256, 0, stream>>>(XL, HC, adj_nn, ptr_nn, isq_nn, conv_root + l * EMB);

        // GCN 2 (net_node edges) + LN + leaky + residual
        k_matmul_mfma<<<NN / 64, 256, 0, stream>>>(HC, reconv_w + (size_t)l * EMB * EMB, reconv_b + l * EMB, XL);
        k_gather2<<<NN / 4, 256, 0, stream>>>(XL, H, adj_net, ptr_net, isq_net, reconv_root + l * EMB,
                                              ln_g + l * EMB, ln_b + l * EMB, out, (l + 1) * EMB);
    }
}

// Round 9
// 1454.442 us; speedup vs baseline: 1.3606x; 1.1707x over previous
//
#include <hip/hip_runtime.h>
#include <hip/hip_bf16.h>

#define NN 200000
#define EE 600000
#define ND 32
#define EMB 128
#define NI_C 120000
#define NEGS 0.1f
#define LNEPS 1e-5f
#define CH 782   // (NN+255)/256 scan chunks

typedef short bf16x8 __attribute__((ext_vector_type(8)));
typedef float f32x4 __attribute__((ext_vector_type(4)));

__device__ __forceinline__ float leakyf(float x) { return x >= 0.0f ? x : NEGS * x; }
__device__ __forceinline__ void fma4(float4& a, float s, const float4& w) {
    a.x = fmaf(s, w.x, a.x); a.y = fmaf(s, w.y, a.y);
    a.z = fmaf(s, w.z, a.z); a.w = fmaf(s, w.w, a.w);
}
__device__ __forceinline__ float bfu2f(unsigned int u) { return __uint_as_float(u << 16); }
__device__ __forceinline__ float bfhi2f(unsigned int u) { return __uint_as_float(u & 0xffff0000u); }
__device__ __forceinline__ unsigned short f2bf_rne(float x) {
    unsigned int u = __float_as_uint(x);
    u = (u + 0x7fffu + ((u >> 16) & 1u)) >> 16;
    return (unsigned short)u;
}

// ---------------- histograms: row (for deg/isq) + col (for CSR) ----------------
__global__ __launch_bounds__(256) void k_hist(const int* __restrict__ ei_nn,
                                              const int* __restrict__ ei_net,
                                              int* __restrict__ cnt_nn, int* __restrict__ cnt_net,
                                              int* __restrict__ ccol_nn, int* __restrict__ ccol_net) {
    int e = blockIdx.x * 256 + threadIdx.x;
    if (e < EE) {
        atomicAdd(&cnt_nn[ei_nn[e]], 1);            // row histogram (deg)
        atomicAdd(&cnt_net[ei_net[e]], 1);
        atomicAdd(&ccol_nn[ei_nn[EE + e]], 1);      // col histogram (CSR)
        atomicAdd(&ccol_net[ei_net[EE + e]], 1);
    }
}

__global__ __launch_bounds__(256) void k_deg(const int* __restrict__ cnt_nn,
                                             const int* __restrict__ cnt_net,
                                             float* __restrict__ isq_nn, float* __restrict__ isq_net) {
    int n = blockIdx.x * 256 + threadIdx.x;
    if (n < NN) {
        isq_nn[n]  = rsqrtf((float)(cnt_nn[n] + 1));
        isq_net[n] = rsqrtf((float)(cnt_net[n] + 1));
    }
}

// ---------------- exclusive scan (3-kernel, 200k ints) ----------------
__global__ __launch_bounds__(256) void k_scan1(const int* __restrict__ cnt,
                                               int* __restrict__ ptr, int* __restrict__ bsum) {
    __shared__ int s[256];
    int t = threadIdx.x, i = blockIdx.x * 256 + t;
    int v = (i < NN) ? cnt[i] : 0;
    s[t] = v; __syncthreads();
    for (int off = 1; off < 256; off <<= 1) {
        int u = (t >= off) ? s[t - off] : 0;
        __syncthreads();
        s[t] += u; __syncthreads();
    }
    if (i < NN) ptr[i] = s[t] - v;
    if (t == 255) bsum[blockIdx.x] = s[255];
}

__global__ __launch_bounds__(1024) void k_scan2(int* __restrict__ bsum) {
    __shared__ int s[1024];
    int t = threadIdx.x;
    int v = (t < CH) ? bsum[t] : 0;
    s[t] = v; __syncthreads();
    for (int off = 1; off < 1024; off <<= 1) {
        int u = (t >= off) ? s[t - off] : 0;
        __syncthreads();
        s[t] += u; __syncthreads();
    }
    if (t < CH) bsum[t] = s[t] - v;   // exclusive block offsets
}

__global__ __launch_bounds__(256) void k_scan3(int* __restrict__ ptr, const int* __restrict__ bsum) {
    int i = blockIdx.x * 256 + threadIdx.x;
    if (i < NN) ptr[i] += bsum[blockIdx.x];
    if (i == 0) ptr[NN] = EE;
}

// ---------------- CSR fill (both directions) ----------------
__global__ __launch_bounds__(256) void k_fill(const int* __restrict__ ei_nn, const int* __restrict__ ei_net,
                                              const int* __restrict__ ptr_nn, const int* __restrict__ ptr_net,
                                              int* __restrict__ cur_nn, int* __restrict__ cur_net,
                                              int* __restrict__ adj_nn, int* __restrict__ adj_net) {
    int e = blockIdx.x * 256 + threadIdx.x;
    if (e < EE) {
        int c1 = ei_nn[EE + e];
        int p1 = ptr_nn[c1] + atomicAdd(&cur_nn[c1], 1);
        adj_nn[p1] = ei_nn[e];
        int c2 = ei_net[EE + e];
        int p2 = ptr_net[c2] + atomicAdd(&cur_net[c2], 1);
        adj_net[p2] = ei_net[e];
    }
}

// ---------------- encoder: h0 = leaky(leaky(x@W1+b1)@W2+b2) ----------------
// R0-verified VALU path, verbatim.
__global__ __launch_bounds__(256) void k_encoder(const float* __restrict__ x,
                                                 const float* __restrict__ w1, const float* __restrict__ b1,
                                                 const float* __restrict__ w2, const float* __restrict__ b2,
                                                 float* __restrict__ H, float* __restrict__ out) {
    __shared__ float4 xs[512];
    __shared__ __align__(16) __hip_bfloat16 hs[64 * 256];
    int tid = threadIdx.x;
    int n0 = blockIdx.x * 64;

    const float4* xg = (const float4*)(x + (size_t)n0 * ND);
    for (int p = tid; p < 512; p += 256) xs[p] = xg[p];
    __syncthreads();

    {
        float w[32];
#pragma unroll
        for (int k = 0; k < 32; k++) w[k] = w1[k * 256 + tid];
        float bj = b1[tid];
        for (int n = 0; n < 64; n++) {
            float acc = bj;
#pragma unroll
            for (int k4 = 0; k4 < 8; k4++) {
                float4 xv = xs[n * 8 + k4];
                acc = fmaf(xv.x, w[4 * k4 + 0], acc);
                acc = fmaf(xv.y, w[4 * k4 + 1], acc);
                acc = fmaf(xv.z, w[4 * k4 + 2], acc);
                acc = fmaf(xv.w, w[4 * k4 + 3], acc);
            }
            hs[n * 256 + tid] = __float2bfloat16(leakyf(acc));
        }
    }
    __syncthreads();

    int tx = tid & 31, ty = tid >> 5;
    float4 bias = ((const float4*)b2)[tx];
    float4 acc[8];
#pragma unroll
    for (int i = 0; i < 8; i++) acc[i] = bias;

    const float4* w2g = (const float4*)w2;
    const unsigned short* hsu = (const unsigned short*)hs;
    for (int k4 = 0; k4 < 64; k4++) {
        float4 w0 = w2g[(4 * k4 + 0) * 32 + tx];
        float4 wv1 = w2g[(4 * k4 + 1) * 32 + tx];
        float4 wv2 = w2g[(4 * k4 + 2) * 32 + tx];
        float4 wv3 = w2g[(4 * k4 + 3) * 32 + tx];
#pragma unroll
        for (int i = 0; i < 8; i++) {
            int n = ty * 8 + i;
            uint2 hv = *(const uint2*)(hsu + n * 256 + 4 * k4);
            float a0 = bfu2f(hv.x & 0xffffu);
            float a1 = bfu2f(hv.x >> 16);
            float a2 = bfu2f(hv.y & 0xffffu);
            float a3 = bfu2f(hv.y >> 16);
            fma4(acc[i], a0, w0); fma4(acc[i], a1, wv1);
            fma4(acc[i], a2, wv2); fma4(acc[i], a3, wv3);
        }
    }
#pragma unroll
    for (int i = 0; i < 8; i++) {
        int n = n0 + ty * 8 + i;
        float4 v;
        v.x = leakyf(acc[i].x); v.y = leakyf(acc[i].y);
        v.z = leakyf(acc[i].z); v.w = leakyf(acc[i].w);
        ((float4*)H)[(size_t)n * 32 + tx] = v;
        if (n < NI_C) ((float4*)out)[(size_t)n * 128 + tx] = v;
    }
}

// ---------------- XL(bf16) = A @ W + b via split-bf16 MFMA (near-fp32 accuracy) ----------------
__global__ __launch_bounds__(256) void k_matmul_mfma(const float* __restrict__ A,
                                                     const float* __restrict__ W,
                                                     const float* __restrict__ bias,
                                                     unsigned short* __restrict__ out) {
    __shared__ unsigned short wt_hi[64][136];   // W^T, pad 8 -> 272B rows, 2-way max aliasing
    __shared__ unsigned short wt_lo[64][136];
    int tid = threadIdx.x;
    int lane = tid & 63, wv = tid >> 6;
    int g = lane >> 4, r = lane & 15;
    const float* arow = A + ((size_t)blockIdx.x * 64 + wv * 16 + r) * 128;

    // Per-lane A fragments: 8 contiguous fp32 at k = kc*32 + g*8, split hi/lo in-register.
    bf16x8 ahi[4], alo[4];
#pragma unroll
    for (int kc = 0; kc < 4; kc++) {
        int kk = kc * 32 + g * 8;
        float4 v0 = *(const float4*)(arow + kk);
        float4 v1 = *(const float4*)(arow + kk + 4);
        float av[8] = {v0.x, v0.y, v0.z, v0.w, v1.x, v1.y, v1.z, v1.w};
#pragma unroll
        for (int i = 0; i < 8; i++) {
            unsigned short h = f2bf_rne(av[i]);
            float hf = __uint_as_float((unsigned int)h << 16);
            unsigned short l = f2bf_rne(av[i] - hf);
            ahi[kc][i] = (short)h;
            alo[kc][i] = (short)l;
        }
    }

    int sc = tid >> 2;            // staging col within half (0..63)
    int sk0 = (tid & 3) * 32;     // staging k base
    for (int h = 0; h < 2; h++) {
        if (h) __syncthreads();   // previous half's LDS reads done before restage
        const float* wp = W + (size_t)h * 64 + sc;
        for (int j = 0; j < 32; j += 4) {
            float b0 = wp[(size_t)(sk0 + j + 0) * 128];
            float b1 = wp[(size_t)(sk0 + j + 1) * 128];
            float b2 = wp[(size_t)(sk0 + j + 2) * 128];
            float b3 = wp[(size_t)(sk0 + j + 3) * 128];
            ushort4 hh, ll;
            hh.x = f2bf_rne(b0); ll.x = f2bf_rne(b0 - __uint_as_float((unsigned int)hh.x << 16));
            hh.y = f2bf_rne(b1); ll.y = f2bf_rne(b1 - __uint_as_float((unsigned int)hh.y << 16));
            hh.z = f2bf_rne(b2); ll.z = f2bf_rne(b2 - __uint_as_float((unsigned int)hh.z << 16));
            hh.w = f2bf_rne(b3); ll.w = f2bf_rne(b3 - __uint_as_float((unsigned int)hh.w << 16));
            *(ushort4*)&wt_hi[sc][sk0 + j] = hh;
            *(ushort4*)&wt_lo[sc][sk0 + j] = ll;
        }
        __syncthreads();

        f32x4 acc[4];
#pragma unroll
        for (int t = 0; t < 4; t++) acc[t] = (f32x4){0.0f, 0.0f, 0.0f, 0.0f};
#pragma unroll
        for (int kc = 0; kc < 4; kc++) {
            int kk = kc * 32 + g * 8;
#pragma unroll
            for (int t = 0; t < 4; t++) {
                bf16x8 bh = *(const bf16x8*)&wt_hi[t * 16 + r][kk];
                bf16x8 bl = *(const bf16x8*)&wt_lo[t * 16 + r][kk];
                acc[t] = __builtin_amdgcn_mfma_f32_16x16x32_bf16(ahi[kc], bh, acc[t], 0, 0, 0);
                acc[t] = __builtin_amdgcn_mfma_f32_16x16x32_bf16(alo[kc], bh, acc[t], 0, 0, 0);
                acc[t] = __builtin_amdgcn_mfma_f32_16x16x32_bf16(ahi[kc], bl, acc[t], 0, 0, 0);
            }
        }

        size_t orow = (size_t)blockIdx.x * 64 + wv * 16 + g * 4;
#pragma unroll
        for (int t = 0; t < 4; t++) {
            int cc = h * 64 + t * 16 + r;
            float bv = bias[cc];
#pragma unroll
            for (int q = 0; q < 4; q++)
                out[(orow + q) * 128 + cc] = f2bf_rne(acc[t][q] + bv);
        }
    }
}

// ---------------- fused gather 1 (bf16 XL, 2 nodes/wave, unroll-2) ----------------
// AGG = isq[n]*sum(isq[r]*relu(XL[r])) + relu(XL[n]+root)*isq[n]^2
__global__ __launch_bounds__(256) void k_gather1(const unsigned short* __restrict__ XLb,
                                                 float* __restrict__ AGG,
                                                 const int* __restrict__ adj, const int* __restrict__ ptr,
                                                 const float* __restrict__ isq,
                                                 const float* __restrict__ root) {
    const uint2* XLq = (const uint2*)XLb;   // 32 uint2 per row (128 bf16)
    int tid = threadIdx.x;
    int c = tid & 31;                        // column quad: bf16 cols 4c..4c+3
    int n = blockIdx.x * 8 + (tid >> 5);     // 8 nodes per 256-thread block
    int s = ptr[n], e = ptr[n + 1];
    float a0 = 0.0f, a1 = 0.0f, a2 = 0.0f, a3 = 0.0f;
    int i = s;
    for (; i + 2 <= e; i += 2) {             // unroll-2: two row loads in flight
        int r0 = adj[i], r1 = adj[i + 1];
        float w0 = isq[r0], w1 = isq[r1];
        uint2 u0 = XLq[(size_t)r0 * 32 + c];
        uint2 u1 = XLq[(size_t)r1 * 32 + c];
        a0 = fmaf(w0, fmaxf(bfu2f(u0.x), 0.0f), a0);
        a1 = fmaf(w0, fmaxf(bfhi2f(u0.x), 0.0f), a1);
        a2 = fmaf(w0, fmaxf(bfu2f(u0.y), 0.0f), a2);
        a3 = fmaf(w0, fmaxf(bfhi2f(u0.y), 0.0f), a3);
        a0 = fmaf(w1, fmaxf(bfu2f(u1.x), 0.0f), a0);
        a1 = fmaf(w1, fmaxf(bfhi2f(u1.x), 0.0f), a1);
        a2 = fmaf(w1, fmaxf(bfu2f(u1.y), 0.0f), a2);
        a3 = fmaf(w1, fmaxf(bfhi2f(u1.y), 0.0f), a3);
    }
    if (i < e) {
        int r0 = adj[i];
        float w0 = isq[r0];
        uint2 u0 = XLq[(size_t)r0 * 32 + c];
        a0 = fmaf(w0, fmaxf(bfu2f(u0.x), 0.0f), a0);
        a1 = fmaf(w0, fmaxf(bfhi2f(u0.x), 0.0f), a1);
        a2 = fmaf(w0, fmaxf(bfu2f(u0.y), 0.0f), a2);
        a3 = fmaf(w0, fmaxf(bfhi2f(u0.y), 0.0f), a3);
    }
    float iq = isq[n];
    float id = iq * iq;
    uint2 su = XLq[(size_t)n * 32 + c];
    float4 rv = ((const float4*)root)[c];
    float4 o;
    o.x = iq * a0 + fmaxf(bfu2f(su.x) + rv.x, 0.0f) * id;
    o.y = iq * a1 + fmaxf(bfhi2f(su.x) + rv.y, 0.0f) * id;
    o.z = iq * a2 + fmaxf(bfu2f(su.y) + rv.z, 0.0f) * id;
    o.w = iq * a3 + fmaxf(bfhi2f(su.y) + rv.w, 0.0f) * id;
    ((float4*)AGG)[(size_t)n * 32 + c] = o;
}

// ---------------- fused gather 2 (bf16 XL, 2 nodes/wave, unroll-2) ----------------
// gather + self + LN + leaky + residual + out slice; LN reduce across 32 lanes.
__global__ __launch_bounds__(256) void k_gather2(const unsigned short* __restrict__ XLb,
                                                 float* __restrict__ H,
                                                 const int* __restrict__ adj, const int* __restrict__ ptr,
                                                 const float* __restrict__ isq,
                                                 const float* __restrict__ root,
                                                 const float* __restrict__ g, const float* __restrict__ b,
                                                 float* __restrict__ out, int layer_off) {
    const uint2* XLq = (const uint2*)XLb;
    int tid = threadIdx.x;
    int c = tid & 31;
    int n = blockIdx.x * 8 + (tid >> 5);
    int s = ptr[n], e = ptr[n + 1];
    float a0 = 0.0f, a1 = 0.0f, a2 = 0.0f, a3 = 0.0f;
    int i = s;
    for (; i + 2 <= e; i += 2) {
        int r0 = adj[i], r1 = adj[i + 1];
        float w0 = isq[r0], w1 = isq[r1];
        uint2 u0 = XLq[(size_t)r0 * 32 + c];
        uint2 u1 = XLq[(size_t)r1 * 32 + c];
        a0 = fmaf(w0, fmaxf(bfu2f(u0.x), 0.0f), a0);
        a1 = fmaf(w0, fmaxf(bfhi2f(u0.x), 0.0f), a1);
        a2 = fmaf(w0, fmaxf(bfu2f(u0.y), 0.0f), a2);
        a3 = fmaf(w0, fmaxf(bfhi2f(u0.y), 0.0f), a3);
        a0 = fmaf(w1, fmaxf(bfu2f(u1.x), 0.0f), a0);
        a1 = fmaf(w1, fmaxf(bfhi2f(u1.x), 0.0f), a1);
        a2 = fmaf(w1, fmaxf(bfu2f(u1.y), 0.0f), a2);
        a3 = fmaf(w1, fmaxf(bfhi2f(u1.y), 0.0f), a3);
    }
    if (i < e) {
        int r0 = adj[i];
        float w0 = isq[r0];
        uint2 u0 = XLq[(size_t)r0 * 32 + c];
        a0 = fmaf(w0, fmaxf(bfu2f(u0.x), 0.0f), a0);
        a1 = fmaf(w0, fmaxf(bfhi2f(u0.x), 0.0f), a1);
        a2 = fmaf(w0, fmaxf(bfu2f(u0.y), 0.0f), a2);
        a3 = fmaf(w0, fmaxf(bfhi2f(u0.y), 0.0f), a3);
    }
    float iq = isq[n];
    float id = iq * iq;
    uint2 su = XLq[(size_t)n * 32 + c];
    float4 rv = ((const float4*)root)[c];
    float t0 = iq * a0 + fmaxf(bfu2f(su.x) + rv.x, 0.0f) * id;
    float t1 = iq * a1 + fmaxf(bfhi2f(su.x) + rv.y, 0.0f) * id;
    float t2 = iq * a2 + fmaxf(bfu2f(su.y) + rv.z, 0.0f) * id;
    float t3 = iq * a3 + fmaxf(bfhi2f(su.y) + rv.w, 0.0f) * id;

    float sm = t0 + t1 + t2 + t3;
#pragma unroll
    for (int off = 16; off; off >>= 1) sm += __shfl_xor(sm, off, 32);
    float mu = sm * (1.0f / 128.0f);
    float d0 = t0 - mu, d1 = t1 - mu, d2 = t2 - mu, d3 = t3 - mu;
    float q = d0 * d0 + d1 * d1 + d2 * d2 + d3 * d3;
#pragma unroll
    for (int off = 16; off; off >>= 1) q += __shfl_xor(q, off, 32);
    float rs = rsqrtf(q * (1.0f / 128.0f) + LNEPS);

    float4 gv = ((const float4*)g)[c];
    float4 bv = ((const float4*)b)[c];
    float y0 = leakyf(d0 * rs * gv.x + bv.x);
    float y1 = leakyf(d1 * rs * gv.y + bv.y);
    float y2 = leakyf(d2 * rs * gv.z + bv.z);
    float y3 = leakyf(d3 * rs * gv.w + bv.w);

    float4* h4 = (float4*)H + (size_t)n * 32 + c;
    float4 hv = *h4;
    float4 o2;
    o2.x = y0 + hv.x; o2.y = y1 + hv.y; o2.z = y2 + hv.z; o2.w = y3 + hv.w;
    *h4 = o2;
    if (n < NI_C) ((float4*)out)[(size_t)n * 128 + (layer_off >> 2) + c] = o2;
}

extern "C" void kernel_launch(void* const* d_in, const int* in_sizes, int n_in,
                              void* d_out, int out_size, void* d_ws, size_t ws_size,
                              hipStream_t stream) {
    const float* x         = (const float*)d_in[0];
    const float* enc_w1    = (const float*)d_in[1];
    const float* enc_b1    = (const float*)d_in[2];
    const float* enc_w2    = (const float*)d_in[3];
    const float* enc_b2    = (const float*)d_in[4];
    const float* conv_w    = (const float*)d_in[5];
    const float* conv_b    = (const float*)d_in[6];
    const float* conv_root = (const float*)d_in[7];
    const float* reconv_w    = (const float*)d_in[8];
    const float* reconv_b    = (const float*)d_in[9];
    const float* reconv_root = (const float*)d_in[10];
    const float* ln_g = (const float*)d_in[11];
    const float* ln_b = (const float*)d_in[12];
    const int* ei_nn  = (const int*)d_in[13];
    const int* ei_net = (const int*)d_in[14];
    float* out = (float*)d_out;

    char* ws = (char*)d_ws;
    size_t off = 0;
    const size_t big = (size_t)NN * EMB * sizeof(float);  // 102.4 MB
    float* H  = (float*)(ws + off); off += big;
    unsigned short* XL = (unsigned short*)(ws + off); off += big;  // bf16, half used
    float* HC = (float*)(ws + off); off += big;
    float* isq_nn  = (float*)(ws + off); off += (size_t)NN * 4;
    float* isq_net = (float*)(ws + off); off += (size_t)NN * 4;
    // histogram block (contiguous for single memset): cnt_nn, cnt_net, ccol_nn, ccol_net
    int* cnt_nn  = (int*)(ws + off); off += (size_t)NN * 4;   // reused as cur_nn after k_deg
    int* cnt_net = (int*)(ws + off); off += (size_t)NN * 4;   // reused as cur_net
    int* ccol_nn  = (int*)(ws + off); off += (size_t)NN * 4;
    int* ccol_net = (int*)(ws + off); off += (size_t)NN * 4;
    int* ptr_nn  = (int*)(ws + off); off += (size_t)(NN + 1) * 4;
    int* ptr_net = (int*)(ws + off); off += (size_t)(NN + 1) * 4;
    int* adj_nn  = (int*)(ws + off); off += (size_t)EE * 4;
    int* adj_net = (int*)(ws + off); off += (size_t)EE * 4;
    int* bsum_nn  = (int*)(ws + off); off += (size_t)1024 * 4;
    int* bsum_net = (int*)(ws + off); off += (size_t)1024 * 4;

    // ---- CSR + degree build (once per launch, reused by all 3 layers) ----
    hipMemsetAsync(cnt_nn, 0, (size_t)NN * 4 * 4, stream);  // all 4 histograms
    k_hist<<<(EE + 255) / 256, 256, 0, stream>>>(ei_nn, ei_net, cnt_nn, cnt_net, ccol_nn, ccol_net);
    k_deg<<<(NN + 255) / 256, 256, 0, stream>>>(cnt_nn, cnt_net, isq_nn, isq_net);
    k_scan1<<<CH, 256, 0, stream>>>(ccol_nn, ptr_nn, bsum_nn);
    k_scan1<<<CH, 256, 0, stream>>>(ccol_net, ptr_net, bsum_net);
    k_scan2<<<1, 1024, 0, stream>>>(bsum_nn);
    k_scan2<<<1, 1024, 0, stream>>>(bsum_net);
    k_scan3<<<CH, 256, 0, stream>>>(ptr_nn, bsum_nn);
    k_scan3<<<CH, 256, 0, stream>>>(ptr_net, bsum_net);
    hipMemsetAsync(cnt_nn, 0, (size_t)NN * 4 * 2, stream);  // zero fill cursors (reuse cnt)
    k_fill<<<(EE + 255) / 256, 256, 0, stream>>>(ei_nn, ei_net, ptr_nn, ptr_net,
                                                 cnt_nn, cnt_net, adj_nn, adj_net);

    // ---- encoder -> H, out[:,0:128] ----
    k_encoder<<<NN / 64, 256, 0, stream>>>(x, enc_w1, enc_b1, enc_w2, enc_b2, H, out);

    for (int l = 0; l < 3; l++) {
        // GCN 1 (node_net edges)
        k_matmul_mfma<<<NN / 64, 256, 0, stream>>>(H, conv_w + (size_t)l * EMB * EMB, conv_b + l * EMB, XL);
        k_gather1<<<NN / 8, 256, 0, stream>>>(XL, HC, adj_nn, ptr_nn, isq_nn, conv_root + l * EMB);

        // GCN 2 (net_node edges) + LN + leaky + residual
        k_matmul_mfma<<<NN / 64, 256, 0, stream>>>(HC, reconv_w + (size_t)l * EMB * EMB, reconv_b + l * EMB, XL);
        k_gather2<<<NN / 8, 256, 0, stream>>>(XL, H, adj_net, ptr_net, isq_net, reconv_root + l * EMB,
                                              ln_g + l * EMB, ln_b + l * EMB, out, (l + 1) * EMB);
    }
}

// Round 13
// 1387.801 us; speedup vs baseline: 1.4259x; 1.0480x over previous
//
#include <hip/hip_runtime.h>
#include <hip/hip_bf16.h>

#define NN 200000
#define EE 600000
#define ND 32
#define EMB 128
#define NI_C 120000
#define NEGS 0.1f
#define LNEPS 1e-5f
#define CH 782   // (NN+255)/256 scan chunks

typedef short bf16x8 __attribute__((ext_vector_type(8)));
typedef float f32x4 __attribute__((ext_vector_type(4)));

__device__ __forceinline__ float leakyf(float x) { return x >= 0.0f ? x : NEGS * x; }
__device__ __forceinline__ void fma4(float4& a, float s, const float4& w) {
    a.x = fmaf(s, w.x, a.x); a.y = fmaf(s, w.y, a.y);
    a.z = fmaf(s, w.z, a.z); a.w = fmaf(s, w.w, a.w);
}
__device__ __forceinline__ float bfu2f(unsigned int u) { return __uint_as_float(u << 16); }
__device__ __forceinline__ float bfhi2f(unsigned int u) { return __uint_as_float(u & 0xffff0000u); }
__device__ __forceinline__ unsigned short f2bf_rne(float x) {
    unsigned int u = __float_as_uint(x);
    u = (u + 0x7fffu + ((u >> 16) & 1u)) >> 16;
    return (unsigned short)u;
}
// accumulate 8 bf16 cols (one uint4) with weight w and relu
__device__ __forceinline__ void acc8(float4& A0, float4& A1, float w, const uint4& u) {
    A0.x = fmaf(w, fmaxf(bfu2f(u.x), 0.0f), A0.x);
    A0.y = fmaf(w, fmaxf(bfhi2f(u.x), 0.0f), A0.y);
    A0.z = fmaf(w, fmaxf(bfu2f(u.y), 0.0f), A0.z);
    A0.w = fmaf(w, fmaxf(bfhi2f(u.y), 0.0f), A0.w);
    A1.x = fmaf(w, fmaxf(bfu2f(u.z), 0.0f), A1.x);
    A1.y = fmaf(w, fmaxf(bfhi2f(u.z), 0.0f), A1.y);
    A1.z = fmaf(w, fmaxf(bfu2f(u.w), 0.0f), A1.z);
    A1.w = fmaf(w, fmaxf(bfhi2f(u.w), 0.0f), A1.w);
}

// ---------------- histograms: row (for deg/isq) + col (for CSR) ----------------
__global__ __launch_bounds__(256) void k_hist(const int* __restrict__ ei_nn,
                                              const int* __restrict__ ei_net,
                                              int* __restrict__ cnt_nn, int* __restrict__ cnt_net,
                                              int* __restrict__ ccol_nn, int* __restrict__ ccol_net) {
    int e = blockIdx.x * 256 + threadIdx.x;
    if (e < EE) {
        atomicAdd(&cnt_nn[ei_nn[e]], 1);            // row histogram (deg)
        atomicAdd(&cnt_net[ei_net[e]], 1);
        atomicAdd(&ccol_nn[ei_nn[EE + e]], 1);      // col histogram (CSR)
        atomicAdd(&ccol_net[ei_net[EE + e]], 1);
    }
}

__global__ __launch_bounds__(256) void k_deg(const int* __restrict__ cnt_nn,
                                             const int* __restrict__ cnt_net,
                                             float* __restrict__ isq_nn, float* __restrict__ isq_net) {
    int n = blockIdx.x * 256 + threadIdx.x;
    if (n < NN) {
        isq_nn[n]  = rsqrtf((float)(cnt_nn[n] + 1));
        isq_net[n] = rsqrtf((float)(cnt_net[n] + 1));
    }
}

// ---------------- exclusive scan (3-kernel, 200k ints) ----------------
__global__ __launch_bounds__(256) void k_scan1(const int* __restrict__ cnt,
                                               int* __restrict__ ptr, int* __restrict__ bsum) {
    __shared__ int s[256];
    int t = threadIdx.x, i = blockIdx.x * 256 + t;
    int v = (i < NN) ? cnt[i] : 0;
    s[t] = v; __syncthreads();
    for (int off = 1; off < 256; off <<= 1) {
        int u = (t >= off) ? s[t - off] : 0;
        __syncthreads();
        s[t] += u; __syncthreads();
    }
    if (i < NN) ptr[i] = s[t] - v;
    if (t == 255) bsum[blockIdx.x] = s[255];
}

__global__ __launch_bounds__(1024) void k_scan2(int* __restrict__ bsum) {
    __shared__ int s[1024];
    int t = threadIdx.x;
    int v = (t < CH) ? bsum[t] : 0;
    s[t] = v; __syncthreads();
    for (int off = 1; off < 1024; off <<= 1) {
        int u = (t >= off) ? s[t - off] : 0;
        __syncthreads();
        s[t] += u; __syncthreads();
    }
    if (t < CH) bsum[t] = s[t] - v;   // exclusive block offsets
}

__global__ __launch_bounds__(256) void k_scan3(int* __restrict__ ptr, const int* __restrict__ bsum) {
    int i = blockIdx.x * 256 + threadIdx.x;
    if (i < NN) ptr[i] += bsum[blockIdx.x];
    if (i == 0) ptr[NN] = EE;
}

// ---------------- CSR fill (both directions) ----------------
__global__ __launch_bounds__(256) void k_fill(const int* __restrict__ ei_nn, const int* __restrict__ ei_net,
                                              const int* __restrict__ ptr_nn, const int* __restrict__ ptr_net,
                                              int* __restrict__ cur_nn, int* __restrict__ cur_net,
                                              int* __restrict__ adj_nn, int* __restrict__ adj_net) {
    int e = blockIdx.x * 256 + threadIdx.x;
    if (e < EE) {
        int c1 = ei_nn[EE + e];
        int p1 = ptr_nn[c1] + atomicAdd(&cur_nn[c1], 1);
        adj_nn[p1] = ei_nn[e];
        int c2 = ei_net[EE + e];
        int p2 = ptr_net[c2] + atomicAdd(&cur_net[c2], 1);
        adj_net[p2] = ei_net[e];
    }
}

// ---------------- encoder: h0 = leaky(leaky(x@W1+b1)@W2+b2) ----------------
// R0-verified VALU path, verbatim (encoder-MFMA line permanently parked: R3/R7/R10).
__global__ __launch_bounds__(256) void k_encoder(const float* __restrict__ x,
                                                 const float* __restrict__ w1, const float* __restrict__ b1,
                                                 const float* __restrict__ w2, const float* __restrict__ b2,
                                                 float* __restrict__ H, float* __restrict__ out) {
    __shared__ float4 xs[512];
    __shared__ __align__(16) __hip_bfloat16 hs[64 * 256];
    int tid = threadIdx.x;
    int n0 = blockIdx.x * 64;

    const float4* xg = (const float4*)(x + (size_t)n0 * ND);
    for (int p = tid; p < 512; p += 256) xs[p] = xg[p];
    __syncthreads();

    {
        float w[32];
#pragma unroll
        for (int k = 0; k < 32; k++) w[k] = w1[k * 256 + tid];
        float bj = b1[tid];
        for (int n = 0; n < 64; n++) {
            float acc = bj;
#pragma unroll
            for (int k4 = 0; k4 < 8; k4++) {
                float4 xv = xs[n * 8 + k4];
                acc = fmaf(xv.x, w[4 * k4 + 0], acc);
                acc = fmaf(xv.y, w[4 * k4 + 1], acc);
                acc = fmaf(xv.z, w[4 * k4 + 2], acc);
                acc = fmaf(xv.w, w[4 * k4 + 3], acc);
            }
            hs[n * 256 + tid] = __float2bfloat16(leakyf(acc));
        }
    }
    __syncthreads();

    int tx = tid & 31, ty = tid >> 5;
    float4 bias = ((const float4*)b2)[tx];
    float4 acc[8];
#pragma unroll
    for (int i = 0; i < 8; i++) acc[i] = bias;

    const float4* w2g = (const float4*)w2;
    const unsigned short* hsu = (const unsigned short*)hs;
    for (int k4 = 0; k4 < 64; k4++) {
        float4 w0 = w2g[(4 * k4 + 0) * 32 + tx];
        float4 wv1 = w2g[(4 * k4 + 1) * 32 + tx];
        float4 wv2 = w2g[(4 * k4 + 2) * 32 + tx];
        float4 wv3 = w2g[(4 * k4 + 3) * 32 + tx];
#pragma unroll
        for (int i = 0; i < 8; i++) {
            int n = ty * 8 + i;
            uint2 hv = *(const uint2*)(hsu + n * 256 + 4 * k4);
            float a0 = bfu2f(hv.x & 0xffffu);
            float a1 = bfu2f(hv.x >> 16);
            float a2 = bfu2f(hv.y & 0xffffu);
            float a3 = bfu2f(hv.y >> 16);
            fma4(acc[i], a0, w0); fma4(acc[i], a1, wv1);
            fma4(acc[i], a2, wv2); fma4(acc[i], a3, wv3);
        }
    }
#pragma unroll
    for (int i = 0; i < 8; i++) {
        int n = n0 + ty * 8 + i;
        float4 v;
        v.x = leakyf(acc[i].x); v.y = leakyf(acc[i].y);
        v.z = leakyf(acc[i].z); v.w = leakyf(acc[i].w);
        ((float4*)H)[(size_t)n * 32 + tx] = v;
        if (n < NI_C) ((float4*)out)[(size_t)n * 128 + tx] = v;
    }
}

// ---------------- XL(bf16) = A @ W + b via split-bf16 MFMA (near-fp32 accuracy) ----------------
__global__ __launch_bounds__(256) void k_matmul_mfma(const float* __restrict__ A,
                                                     const float* __restrict__ W,
                                                     const float* __restrict__ bias,
                                                     unsigned short* __restrict__ out) {
    __shared__ unsigned short wt_hi[64][136];   // W^T, pad 8 -> 272B rows, 2-way max aliasing
    __shared__ unsigned short wt_lo[64][136];
    int tid = threadIdx.x;
    int lane = tid & 63, wv = tid >> 6;
    int g = lane >> 4, r = lane & 15;
    const float* arow = A + ((size_t)blockIdx.x * 64 + wv * 16 + r) * 128;

    // Per-lane A fragments: 8 contiguous fp32 at k = kc*32 + g*8, split hi/lo in-register.
    bf16x8 ahi[4], alo[4];
#pragma unroll
    for (int kc = 0; kc < 4; kc++) {
        int kk = kc * 32 + g * 8;
        float4 v0 = *(const float4*)(arow + kk);
        float4 v1 = *(const float4*)(arow + kk + 4);
        float av[8] = {v0.x, v0.y, v0.z, v0.w, v1.x, v1.y, v1.z, v1.w};
#pragma unroll
        for (int i = 0; i < 8; i++) {
            unsigned short h = f2bf_rne(av[i]);
            float hf = __uint_as_float((unsigned int)h << 16);
            unsigned short l = f2bf_rne(av[i] - hf);
            ahi[kc][i] = (short)h;
            alo[kc][i] = (short)l;
        }
    }

    int sc = tid >> 2;            // staging col within half (0..63)
    int sk0 = (tid & 3) * 32;     // staging k base
    for (int h = 0; h < 2; h++) {
        if (h) __syncthreads();   // previous half's LDS reads done before restage
        const float* wp = W + (size_t)h * 64 + sc;
        for (int j = 0; j < 32; j += 4) {
            float b0 = wp[(size_t)(sk0 + j + 0) * 128];
            float b1 = wp[(size_t)(sk0 + j + 1) * 128];
            float b2 = wp[(size_t)(sk0 + j + 2) * 128];
            float b3 = wp[(size_t)(sk0 + j + 3) * 128];
            ushort4 hh, ll;
            hh.x = f2bf_rne(b0); ll.x = f2bf_rne(b0 - __uint_as_float((unsigned int)hh.x << 16));
            hh.y = f2bf_rne(b1); ll.y = f2bf_rne(b1 - __uint_as_float((unsigned int)hh.y << 16));
            hh.z = f2bf_rne(b2); ll.z = f2bf_rne(b2 - __uint_as_float((unsigned int)hh.z << 16));
            hh.w = f2bf_rne(b3); ll.w = f2bf_rne(b3 - __uint_as_float((unsigned int)hh.w << 16));
            *(ushort4*)&wt_hi[sc][sk0 + j] = hh;
            *(ushort4*)&wt_lo[sc][sk0 + j] = ll;
        }
        __syncthreads();

        f32x4 acc[4];
#pragma unroll
        for (int t = 0; t < 4; t++) acc[t] = (f32x4){0.0f, 0.0f, 0.0f, 0.0f};
#pragma unroll
        for (int kc = 0; kc < 4; kc++) {
            int kk = kc * 32 + g * 8;
#pragma unroll
            for (int t = 0; t < 4; t++) {
                bf16x8 bh = *(const bf16x8*)&wt_hi[t * 16 + r][kk];
                bf16x8 bl = *(const bf16x8*)&wt_lo[t * 16 + r][kk];
                acc[t] = __builtin_amdgcn_mfma_f32_16x16x32_bf16(ahi[kc], bh, acc[t], 0, 0, 0);
                acc[t] = __builtin_amdgcn_mfma_f32_16x16x32_bf16(alo[kc], bh, acc[t], 0, 0, 0);
                acc[t] = __builtin_amdgcn_mfma_f32_16x16x32_bf16(ahi[kc], bl, acc[t], 0, 0, 0);
            }
        }

        size_t orow = (size_t)blockIdx.x * 64 + wv * 16 + g * 4;
#pragma unroll
        for (int t = 0; t < 4; t++) {
            int cc = h * 64 + t * 16 + r;
            float bv = bias[cc];
#pragma unroll
            for (int q = 0; q < 4; q++)
                out[(orow + q) * 128 + cc] = f2bf_rne(acc[t][q] + bv);
        }
    }
}

// ---------------- fused gather 1 (bf16 XL, 4 nodes/wave, 16 lanes/node, unroll-2) ----------------
// AGG = isq[n]*sum(isq[r]*relu(XL[r])) + relu(XL[n]+root)*isq[n]^2
__global__ __launch_bounds__(256) void k_gather1(const unsigned short* __restrict__ XLb,
                                                 float* __restrict__ AGG,
                                                 const int* __restrict__ adj, const int* __restrict__ ptr,
                                                 const float* __restrict__ isq,
                                                 const float* __restrict__ root) {
    const uint4* XLq = (const uint4*)XLb;    // 16 uint4 per row (128 bf16)
    int tid = threadIdx.x;
    int c = tid & 15;                        // col octet: bf16 cols 8c..8c+7
    int n = blockIdx.x * 16 + (tid >> 4);    // 16 nodes per 256-thread block
    int s = ptr[n], e = ptr[n + 1];
    float4 A0 = {0.0f, 0.0f, 0.0f, 0.0f}, A1 = {0.0f, 0.0f, 0.0f, 0.0f};
    int i = s;
    for (; i + 2 <= e; i += 2) {             // unroll-2: two row loads in flight
        int r0 = adj[i], r1 = adj[i + 1];
        float w0 = isq[r0], w1 = isq[r1];
        uint4 u0 = XLq[(size_t)r0 * 16 + c];
        uint4 u1 = XLq[(size_t)r1 * 16 + c];
        acc8(A0, A1, w0, u0);
        acc8(A0, A1, w1, u1);
    }
    if (i < e) {
        int r0 = adj[i];
        float w0 = isq[r0];
        uint4 u0 = XLq[(size_t)r0 * 16 + c];
        acc8(A0, A1, w0, u0);
    }
    float iq = isq[n];
    float id = iq * iq;
    uint4 su = XLq[(size_t)n * 16 + c];
    float4 rv0 = ((const float4*)root)[2 * c];
    float4 rv1 = ((const float4*)root)[2 * c + 1];
    float4 o0, o1;
    o0.x = iq * A0.x + fmaxf(bfu2f(su.x)  + rv0.x, 0.0f) * id;
    o0.y = iq * A0.y + fmaxf(bfhi2f(su.x) + rv0.y, 0.0f) * id;
    o0.z = iq * A0.z + fmaxf(bfu2f(su.y)  + rv0.z, 0.0f) * id;
    o0.w = iq * A0.w + fmaxf(bfhi2f(su.y) + rv0.w, 0.0f) * id;
    o1.x = iq * A1.x + fmaxf(bfu2f(su.z)  + rv1.x, 0.0f) * id;
    o1.y = iq * A1.y + fmaxf(bfhi2f(su.z) + rv1.y, 0.0f) * id;
    o1.z = iq * A1.z + fmaxf(bfu2f(su.w)  + rv1.z, 0.0f) * id;
    o1.w = iq * A1.w + fmaxf(bfhi2f(su.w) + rv1.w, 0.0f) * id;
    float4* ag = (float4*)AGG + (size_t)n * 32 + 2 * c;
    ag[0] = o0;
    ag[1] = o1;
}

// ---------------- fused gather 2 (bf16 XL, 4 nodes/wave, 16 lanes/node, unroll-2) ----------------
// gather + self + LN + leaky + residual + out slice; LN reduce across 16 lanes x 8 vals.
__global__ __launch_bounds__(256) void k_gather2(const unsigned short* __restrict__ XLb,
                                                 float* __restrict__ H,
                                                 const int* __restrict__ adj, const int* __restrict__ ptr,
                                                 const float* __restrict__ isq,
                                                 const float* __restrict__ root,
                                                 const float* __restrict__ g, const float* __restrict__ b,
                                                 float* __restrict__ out, int layer_off) {
    const uint4* XLq = (const uint4*)XLb;
    int tid = threadIdx.x;
    int c = tid & 15;
    int n = blockIdx.x * 16 + (tid >> 4);
    int s = ptr[n], e = ptr[n + 1];
    float4 A0 = {0.0f, 0.0f, 0.0f, 0.0f}, A1 = {0.0f, 0.0f, 0.0f, 0.0f};
    int i = s;
    for (; i + 2 <= e; i += 2) {
        int r0 = adj[i], r1 = adj[i + 1];
        float w0 = isq[r0], w1 = isq[r1];
        uint4 u0 = XLq[(size_t)r0 * 16 + c];
        uint4 u1 = XLq[(size_t)r1 * 16 + c];
        acc8(A0, A1, w0, u0);
        acc8(A0, A1, w1, u1);
    }
    if (i < e) {
        int r0 = adj[i];
        float w0 = isq[r0];
        uint4 u0 = XLq[(size_t)r0 * 16 + c];
        acc8(A0, A1, w0, u0);
    }
    float iq = isq[n];
    float id = iq * iq;
    uint4 su = XLq[(size_t)n * 16 + c];
    float4 rv0 = ((const float4*)root)[2 * c];
    float4 rv1 = ((const float4*)root)[2 * c + 1];
    float t0 = iq * A0.x + fmaxf(bfu2f(su.x)  + rv0.x, 0.0f) * id;
    float t1 = iq * A0.y + fmaxf(bfhi2f(su.x) + rv0.y, 0.0f) * id;
    float t2 = iq * A0.z + fmaxf(bfu2f(su.y)  + rv0.z, 0.0f) * id;
    float t3 = iq * A0.w + fmaxf(bfhi2f(su.y) + rv0.w, 0.0f) * id;
    float t4 = iq * A1.x + fmaxf(bfu2f(su.z)  + rv1.x, 0.0f) * id;
    float t5 = iq * A1.y + fmaxf(bfhi2f(su.z) + rv1.y, 0.0f) * id;
    float t6 = iq * A1.z + fmaxf(bfu2f(su.w)  + rv1.z, 0.0f) * id;
    float t7 = iq * A1.w + fmaxf(bfhi2f(su.w) + rv1.w, 0.0f) * id;

    float sm = ((t0 + t1) + (t2 + t3)) + ((t4 + t5) + (t6 + t7));
#pragma unroll
    for (int off = 8; off; off >>= 1) sm += __shfl_xor(sm, off, 16);
    float mu = sm * (1.0f / 128.0f);
    float d0 = t0 - mu, d1 = t1 - mu, d2 = t2 - mu, d3 = t3 - mu;
    float d4 = t4 - mu, d5 = t5 - mu, d6 = t6 - mu, d7 = t7 - mu;
    float q = ((d0 * d0 + d1 * d1) + (d2 * d2 + d3 * d3))
            + ((d4 * d4 + d5 * d5) + (d6 * d6 + d7 * d7));
#pragma unroll
    for (int off = 8; off; off >>= 1) q += __shfl_xor(q, off, 16);
    float rs = rsqrtf(q * (1.0f / 128.0f) + LNEPS);

    float4 gv0 = ((const float4*)g)[2 * c];
    float4 gv1 = ((const float4*)g)[2 * c + 1];
    float4 bv0 = ((const float4*)b)[2 * c];
    float4 bv1 = ((const float4*)b)[2 * c + 1];
    float y0 = leakyf(d0 * rs * gv0.x + bv0.x);
    float y1 = leakyf(d1 * rs * gv0.y + bv0.y);
    float y2 = leakyf(d2 * rs * gv0.z + bv0.z);
    float y3 = leakyf(d3 * rs * gv0.w + bv0.w);
    float y4 = leakyf(d4 * rs * gv1.x + bv1.x);
    float y5 = leakyf(d5 * rs * gv1.y + bv1.y);
    float y6 = leakyf(d6 * rs * gv1.z + bv1.z);
    float y7 = leakyf(d7 * rs * gv1.w + bv1.w);

    float4* h4 = (float4*)H + (size_t)n * 32 + 2 * c;
    float4 hv0 = h4[0];
    float4 hv1 = h4[1];
    float4 o0, o1;
    o0.x = y0 + hv0.x; o0.y = y1 + hv0.y; o0.z = y2 + hv0.z; o0.w = y3 + hv0.w;
    o1.x = y4 + hv1.x; o1.y = y5 + hv1.y; o1.z = y6 + hv1.z; o1.w = y7 + hv1.w;
    h4[0] = o0;
    h4[1] = o1;
    if (n < NI_C) {
        float4* og = (float4*)out + (size_t)n * 128 + (layer_off >> 2) + 2 * c;
        og[0] = o0;
        og[1] = o1;
    }
}

extern "C" void kernel_launch(void* const* d_in, const int* in_sizes, int n_in,
                              void* d_out, int out_size, void* d_ws, size_t ws_size,
                              hipStream_t stream) {
    const float* x         = (const float*)d_in[0];
    const float* enc_w1    = (const float*)d_in[1];
    const float* enc_b1    = (const float*)d_in[2];
    const float* enc_w2    = (const float*)d_in[3];
    const float* enc_b2    = (const float*)d_in[4];
    const float* conv_w    = (const float*)d_in[5];
    const float* conv_b    = (const float*)d_in[6];
    const float* conv_root = (const float*)d_in[7];
    const float* reconv_w    = (const float*)d_in[8];
    const float* reconv_b    = (const float*)d_in[9];
    const float* reconv_root = (const float*)d_in[10];
    const float* ln_g = (const float*)d_in[11];
    const float* ln_b = (const float*)d_in[12];
    const int* ei_nn  = (const int*)d_in[13];
    const int* ei_net = (const int*)d_in[14];
    float* out = (float*)d_out;

    char* ws = (char*)d_ws;
    size_t off = 0;
    const size_t big = (size_t)NN * EMB * sizeof(float);  // 102.4 MB
    float* H  = (float*)(ws + off); off += big;
    unsigned short* XL = (unsigned short*)(ws + off); off += big;  // bf16, half used
    float* HC = (float*)(ws + off); off += big;
    float* isq_nn  = (float*)(ws + off); off += (size_t)NN * 4;
    float* isq_net = (float*)(ws + off); off += (size_t)NN * 4;
    // histogram block (contiguous for single memset): cnt_nn, cnt_net, ccol_nn, ccol_net
    int* cnt_nn  = (int*)(ws + off); off += (size_t)NN * 4;   // reused as cur_nn after k_deg
    int* cnt_net = (int*)(ws + off); off += (size_t)NN * 4;   // reused as cur_net
    int* ccol_nn  = (int*)(ws + off); off += (size_t)NN * 4;
    int* ccol_net = (int*)(ws + off); off += (size_t)NN * 4;
    int* ptr_nn  = (int*)(ws + off); off += (size_t)(NN + 1) * 4;
    int* ptr_net = (int*)(ws + off); off += (size_t)(NN + 1) * 4;
    int* adj_nn  = (int*)(ws + off); off += (size_t)EE * 4;
    int* adj_net = (int*)(ws + off); off += (size_t)EE * 4;
    int* bsum_nn  = (int*)(ws + off); off += (size_t)1024 * 4;
    int* bsum_net = (int*)(ws + off); off += (size_t)1024 * 4;

    // ---- CSR + degree build (once per launch, reused by all 3 layers) ----
    hipMemsetAsync(cnt_nn, 0, (size_t)NN * 4 * 4, stream);  // all 4 histograms
    k_hist<<<(EE + 255) / 256, 256, 0, stream>>>(ei_nn, ei_net, cnt_nn, cnt_net, ccol_nn, ccol_net);
    k_deg<<<(NN + 255) / 256, 256, 0, stream>>>(cnt_nn, cnt_net, isq_nn, isq_net);
    k_scan1<<<CH, 256, 0, stream>>>(ccol_nn, ptr_nn, bsum_nn);
    k_scan1<<<CH, 256, 0, stream>>>(ccol_net, ptr_net, bsum_net);
    k_scan2<<<1, 1024, 0, stream>>>(bsum_nn);
    k_scan2<<<1, 1024, 0, stream>>>(bsum_net);
    k_scan3<<<CH, 256, 0, stream>>>(ptr_nn, bsum_nn);
    k_scan3<<<CH, 256, 0, stream>>>(ptr_net, bsum_net);
    hipMemsetAsync(cnt_nn, 0, (size_t)NN * 4 * 2, stream);  // zero fill cursors (reuse cnt)
    k_fill<<<(EE + 255) / 256, 256, 0, stream>>>(ei_nn, ei_net, ptr_nn, ptr_net,
                                                 cnt_nn, cnt_net, adj_nn, adj_net);

    // ---- encoder -> H, out[:,0:128] ----
    k_encoder<<<NN / 64, 256, 0, stream>>>(x, enc_w1, enc_b1, enc_w2, enc_b2, H, out);

    for (int l = 0; l < 3; l++) {
        // GCN 1 (node_net edges)
        k_matmul_mfma<<<NN / 64, 256, 0, stream>>>(H, conv_w + (size_t)l * EMB * EMB, conv_b + l * EMB, XL);
        k_gather1<<<NN / 16, 256, 0, stream>>>(XL, HC, adj_nn, ptr_nn, isq_nn, conv_root + l * EMB);

        // GCN 2 (net_node edges) + LN + leaky + residual
        k_matmul_mfma<<<NN / 64, 256, 0, stream>>>(HC, reconv_w + (size_t)l * EMB * EMB, reconv_b + l * EMB, XL);
        k_gather2<<<NN / 16, 256, 0, stream>>>(XL, H, adj_net, ptr_net, isq_net, reconv_root + l * EMB,
                                               ln_g + l * EMB, ln_b + l * EMB, out, (l + 1) * EMB);
    }
}

// Round 16
// 1293.884 us; speedup vs baseline: 1.5294x; 1.0726x over previous
//
#include <hip/hip_runtime.h>
#include <hip/hip_bf16.h>

#define NN 200000
#define EE 600000
#define ND 32
#define EMB 128
#define NI_C 120000
#define NEGS 0.1f
#define LNEPS 1e-5f
#define CH 782   // (NN+255)/256 scan chunks

typedef short bf16x8 __attribute__((ext_vector_type(8)));
typedef float f32x4 __attribute__((ext_vector_type(4)));

__device__ __forceinline__ float leakyf(float x) { return x >= 0.0f ? x : NEGS * x; }
__device__ __forceinline__ void fma4(float4& a, float s, const float4& w) {
    a.x = fmaf(s, w.x, a.x); a.y = fmaf(s, w.y, a.y);
    a.z = fmaf(s, w.z, a.z); a.w = fmaf(s, w.w, a.w);
}
__device__ __forceinline__ float bfu2f(unsigned int u) { return __uint_as_float(u << 16); }
__device__ __forceinline__ float bfhi2f(unsigned int u) { return __uint_as_float(u & 0xffff0000u); }
__device__ __forceinline__ unsigned short f2bf_rne(float x) {
    unsigned int u = __float_as_uint(x);
    u = (u + 0x7fffu + ((u >> 16) & 1u)) >> 16;
    return (unsigned short)u;
}
__device__ __forceinline__ unsigned int pk2bf(float lo, float hi) {
    return (unsigned int)f2bf_rne(lo) | ((unsigned int)f2bf_rne(hi) << 16);
}
// accumulate 8 bf16 cols (one uint4) with weight w and relu
__device__ __forceinline__ void acc8(float4& A0, float4& A1, float w, const uint4& u) {
    A0.x = fmaf(w, fmaxf(bfu2f(u.x), 0.0f), A0.x);
    A0.y = fmaf(w, fmaxf(bfhi2f(u.x), 0.0f), A0.y);
    A0.z = fmaf(w, fmaxf(bfu2f(u.y), 0.0f), A0.z);
    A0.w = fmaf(w, fmaxf(bfhi2f(u.y), 0.0f), A0.w);
    A1.x = fmaf(w, fmaxf(bfu2f(u.z), 0.0f), A1.x);
    A1.y = fmaf(w, fmaxf(bfhi2f(u.z), 0.0f), A1.y);
    A1.z = fmaf(w, fmaxf(bfu2f(u.w), 0.0f), A1.z);
    A1.w = fmaf(w, fmaxf(bfhi2f(u.w), 0.0f), A1.w);
}

// ---------------- histograms: row (for deg/isq) + col (for CSR) ----------------
__global__ __launch_bounds__(256) void k_hist(const int* __restrict__ ei_nn,
                                              const int* __restrict__ ei_net,
                                              int* __restrict__ cnt_nn, int* __restrict__ cnt_net,
                                              int* __restrict__ ccol_nn, int* __restrict__ ccol_net) {
    int e = blockIdx.x * 256 + threadIdx.x;
    if (e < EE) {
        atomicAdd(&cnt_nn[ei_nn[e]], 1);            // row histogram (deg)
        atomicAdd(&cnt_net[ei_net[e]], 1);
        atomicAdd(&ccol_nn[ei_nn[EE + e]], 1);      // col histogram (CSR)
        atomicAdd(&ccol_net[ei_net[EE + e]], 1);
    }
}

__global__ __launch_bounds__(256) void k_deg(const int* __restrict__ cnt_nn,
                                             const int* __restrict__ cnt_net,
                                             float* __restrict__ isq_nn, float* __restrict__ isq_net) {
    int n = blockIdx.x * 256 + threadIdx.x;
    if (n < NN) {
        isq_nn[n]  = rsqrtf((float)(cnt_nn[n] + 1));
        isq_net[n] = rsqrtf((float)(cnt_net[n] + 1));
    }
}

// ---------------- exclusive scan (3-kernel, 200k ints) ----------------
__global__ __launch_bounds__(256) void k_scan1(const int* __restrict__ cnt,
                                               int* __restrict__ ptr, int* __restrict__ bsum) {
    __shared__ int s[256];
    int t = threadIdx.x, i = blockIdx.x * 256 + t;
    int v = (i < NN) ? cnt[i] : 0;
    s[t] = v; __syncthreads();
    for (int off = 1; off < 256; off <<= 1) {
        int u = (t >= off) ? s[t - off] : 0;
        __syncthreads();
        s[t] += u; __syncthreads();
    }
    if (i < NN) ptr[i] = s[t] - v;
    if (t == 255) bsum[blockIdx.x] = s[255];
}

__global__ __launch_bounds__(1024) void k_scan2(int* __restrict__ bsum) {
    __shared__ int s[1024];
    int t = threadIdx.x;
    int v = (t < CH) ? bsum[t] : 0;
    s[t] = v; __syncthreads();
    for (int off = 1; off < 1024; off <<= 1) {
        int u = (t >= off) ? s[t - off] : 0;
        __syncthreads();
        s[t] += u; __syncthreads();
    }
    if (t < CH) bsum[t] = s[t] - v;   // exclusive block offsets
}

__global__ __launch_bounds__(256) void k_scan3(int* __restrict__ ptr, const int* __restrict__ bsum) {
    int i = blockIdx.x * 256 + threadIdx.x;
    if (i < NN) ptr[i] += bsum[blockIdx.x];
    if (i == 0) ptr[NN] = EE;
}

// ---------------- CSR fill (both directions) ----------------
__global__ __launch_bounds__(256) void k_fill(const int* __restrict__ ei_nn, const int* __restrict__ ei_net,
                                              const int* __restrict__ ptr_nn, const int* __restrict__ ptr_net,
                                              int* __restrict__ cur_nn, int* __restrict__ cur_net,
                                              int* __restrict__ adj_nn, int* __restrict__ adj_net) {
    int e = blockIdx.x * 256 + threadIdx.x;
    if (e < EE) {
        int c1 = ei_nn[EE + e];
        int p1 = ptr_nn[c1] + atomicAdd(&cur_nn[c1], 1);
        adj_nn[p1] = ei_nn[e];
        int c2 = ei_net[EE + e];
        int p2 = ptr_net[c2] + atomicAdd(&cur_net[c2], 1);
        adj_net[p2] = ei_net[e];
    }
}

// ---------------- encoder: h0 = leaky(leaky(x@W1+b1)@W2+b2) ----------------
// R0-verified VALU path, verbatim (encoder-MFMA line permanently parked: R3/R7/R10).
__global__ __launch_bounds__(256) void k_encoder(const float* __restrict__ x,
                                                 const float* __restrict__ w1, const float* __restrict__ b1,
                                                 const float* __restrict__ w2, const float* __restrict__ b2,
                                                 float* __restrict__ H, float* __restrict__ out) {
    __shared__ float4 xs[512];
    __shared__ __align__(16) __hip_bfloat16 hs[64 * 256];
    int tid = threadIdx.x;
    int n0 = blockIdx.x * 64;

    const float4* xg = (const float4*)(x + (size_t)n0 * ND);
    for (int p = tid; p < 512; p += 256) xs[p] = xg[p];
    __syncthreads();

    {
        float w[32];
#pragma unroll
        for (int k = 0; k < 32; k++) w[k] = w1[k * 256 + tid];
        float bj = b1[tid];
        for (int n = 0; n < 64; n++) {
            float acc = bj;
#pragma unroll
            for (int k4 = 0; k4 < 8; k4++) {
                float4 xv = xs[n * 8 + k4];
                acc = fmaf(xv.x, w[4 * k4 + 0], acc);
                acc = fmaf(xv.y, w[4 * k4 + 1], acc);
                acc = fmaf(xv.z, w[4 * k4 + 2], acc);
                acc = fmaf(xv.w, w[4 * k4 + 3], acc);
            }
            hs[n * 256 + tid] = __float2bfloat16(leakyf(acc));
        }
    }
    __syncthreads();

    int tx = tid & 31, ty = tid >> 5;
    float4 bias = ((const float4*)b2)[tx];
    float4 acc[8];
#pragma unroll
    for (int i = 0; i < 8; i++) acc[i] = bias;

    const float4* w2g = (const float4*)w2;
    const unsigned short* hsu = (const unsigned short*)hs;
    for (int k4 = 0; k4 < 64; k4++) {
        float4 w0 = w2g[(4 * k4 + 0) * 32 + tx];
        float4 wv1 = w2g[(4 * k4 + 1) * 32 + tx];
        float4 wv2 = w2g[(4 * k4 + 2) * 32 + tx];
        float4 wv3 = w2g[(4 * k4 + 3) * 32 + tx];
#pragma unroll
        for (int i = 0; i < 8; i++) {
            int n = ty * 8 + i;
            uint2 hv = *(const uint2*)(hsu + n * 256 + 4 * k4);
            float a0 = bfu2f(hv.x & 0xffffu);
            float a1 = bfu2f(hv.x >> 16);
            float a2 = bfu2f(hv.y & 0xffffu);
            float a3 = bfu2f(hv.y >> 16);
            fma4(acc[i], a0, w0); fma4(acc[i], a1, wv1);
            fma4(acc[i], a2, wv2); fma4(acc[i], a3, wv3);
        }
    }
#pragma unroll
    for (int i = 0; i < 8; i++) {
        int n = n0 + ty * 8 + i;
        float4 v;
        v.x = leakyf(acc[i].x); v.y = leakyf(acc[i].y);
        v.z = leakyf(acc[i].z); v.w = leakyf(acc[i].w);
        ((float4*)H)[(size_t)n * 32 + tx] = v;
        if (n < NI_C) ((float4*)out)[(size_t)n * 128 + tx] = v;
    }
}

// ---------------- XL(bf16) = A(fp32) @ W + b via split-bf16 MFMA (3-term) ----------------
__global__ __launch_bounds__(256) void k_matmul_mfma(const float* __restrict__ A,
                                                     const float* __restrict__ W,
                                                     const float* __restrict__ bias,
                                                     unsigned short* __restrict__ out) {
    __shared__ unsigned short wt_hi[64][136];   // W^T, pad 8 -> 272B rows, 2-way max aliasing
    __shared__ unsigned short wt_lo[64][136];
    int tid = threadIdx.x;
    int lane = tid & 63, wv = tid >> 6;
    int g = lane >> 4, r = lane & 15;
    const float* arow = A + ((size_t)blockIdx.x * 64 + wv * 16 + r) * 128;

    // Per-lane A fragments: 8 contiguous fp32 at k = kc*32 + g*8, split hi/lo in-register.
    bf16x8 ahi[4], alo[4];
#pragma unroll
    for (int kc = 0; kc < 4; kc++) {
        int kk = kc * 32 + g * 8;
        float4 v0 = *(const float4*)(arow + kk);
        float4 v1 = *(const float4*)(arow + kk + 4);
        float av[8] = {v0.x, v0.y, v0.z, v0.w, v1.x, v1.y, v1.z, v1.w};
#pragma unroll
        for (int i = 0; i < 8; i++) {
            unsigned short h = f2bf_rne(av[i]);
            float hf = __uint_as_float((unsigned int)h << 16);
            unsigned short l = f2bf_rne(av[i] - hf);
            ahi[kc][i] = (short)h;
            alo[kc][i] = (short)l;
        }
    }

    int sc = tid >> 2;            // staging col within half (0..63)
    int sk0 = (tid & 3) * 32;     // staging k base
    for (int h = 0; h < 2; h++) {
        if (h) __syncthreads();   // previous half's LDS reads done before restage
        const float* wp = W + (size_t)h * 64 + sc;
        for (int j = 0; j < 32; j += 4) {
            float b0 = wp[(size_t)(sk0 + j + 0) * 128];
            float b1 = wp[(size_t)(sk0 + j + 1) * 128];
            float b2 = wp[(size_t)(sk0 + j + 2) * 128];
            float b3 = wp[(size_t)(sk0 + j + 3) * 128];
            ushort4 hh, ll;
            hh.x = f2bf_rne(b0); ll.x = f2bf_rne(b0 - __uint_as_float((unsigned int)hh.x << 16));
            hh.y = f2bf_rne(b1); ll.y = f2bf_rne(b1 - __uint_as_float((unsigned int)hh.y << 16));
            hh.z = f2bf_rne(b2); ll.z = f2bf_rne(b2 - __uint_as_float((unsigned int)hh.z << 16));
            hh.w = f2bf_rne(b3); ll.w = f2bf_rne(b3 - __uint_as_float((unsigned int)hh.w << 16));
            *(ushort4*)&wt_hi[sc][sk0 + j] = hh;
            *(ushort4*)&wt_lo[sc][sk0 + j] = ll;
        }
        __syncthreads();

        f32x4 acc[4];
#pragma unroll
        for (int t = 0; t < 4; t++) acc[t] = (f32x4){0.0f, 0.0f, 0.0f, 0.0f};
#pragma unroll
        for (int kc = 0; kc < 4; kc++) {
            int kk = kc * 32 + g * 8;
#pragma unroll
            for (int t = 0; t < 4; t++) {
                bf16x8 bh = *(const bf16x8*)&wt_hi[t * 16 + r][kk];
                bf16x8 bl = *(const bf16x8*)&wt_lo[t * 16 + r][kk];
                acc[t] = __builtin_amdgcn_mfma_f32_16x16x32_bf16(ahi[kc], bh, acc[t], 0, 0, 0);
                acc[t] = __builtin_amdgcn_mfma_f32_16x16x32_bf16(alo[kc], bh, acc[t], 0, 0, 0);
                acc[t] = __builtin_amdgcn_mfma_f32_16x16x32_bf16(ahi[kc], bl, acc[t], 0, 0, 0);
            }
        }

        size_t orow = (size_t)blockIdx.x * 64 + wv * 16 + g * 4;
#pragma unroll
        for (int t = 0; t < 4; t++) {
            int cc = h * 64 + t * 16 + r;
            float bv = bias[cc];
#pragma unroll
            for (int q = 0; q < 4; q++)
                out[(orow + q) * 128 + cc] = f2bf_rne(acc[t][q] + bv);
        }
    }
}

// ---------------- XL(bf16) = A(bf16) @ W + b: identical structure, A loaded directly ----------------
// Only the A-path differs from the verified k_matmul_mfma: bf16x8 global load, 2-term MFMA.
__global__ __launch_bounds__(256) void k_matmul_mfma_b16(const unsigned short* __restrict__ A,
                                                         const float* __restrict__ W,
                                                         const float* __restrict__ bias,
                                                         unsigned short* __restrict__ out) {
    __shared__ unsigned short wt_hi[64][136];
    __shared__ unsigned short wt_lo[64][136];
    int tid = threadIdx.x;
    int lane = tid & 63, wv = tid >> 6;
    int g = lane >> 4, r = lane & 15;
    const unsigned short* arow = A + ((size_t)blockIdx.x * 64 + wv * 16 + r) * 128;

    bf16x8 ahi[4];
#pragma unroll
    for (int kc = 0; kc < 4; kc++)
        ahi[kc] = *(const bf16x8*)(arow + kc * 32 + g * 8);

    int sc = tid >> 2;            // staging col within half (0..63)
    int sk0 = (tid & 3) * 32;     // staging k base
    for (int h = 0; h < 2; h++) {
        if (h) __syncthreads();   // previous half's LDS reads done before restage
        const float* wp = W + (size_t)h * 64 + sc;
        for (int j = 0; j < 32; j += 4) {
            float b0 = wp[(size_t)(sk0 + j + 0) * 128];
            float b1 = wp[(size_t)(sk0 + j + 1) * 128];
            float b2 = wp[(size_t)(sk0 + j + 2) * 128];
            float b3 = wp[(size_t)(sk0 + j + 3) * 128];
            ushort4 hh, ll;
            hh.x = f2bf_rne(b0); ll.x = f2bf_rne(b0 - __uint_as_float((unsigned int)hh.x << 16));
            hh.y = f2bf_rne(b1); ll.y = f2bf_rne(b1 - __uint_as_float((unsigned int)hh.y << 16));
            hh.z = f2bf_rne(b2); ll.z = f2bf_rne(b2 - __uint_as_float((unsigned int)hh.z << 16));
            hh.w = f2bf_rne(b3); ll.w = f2bf_rne(b3 - __uint_as_float((unsigned int)hh.w << 16));
            *(ushort4*)&wt_hi[sc][sk0 + j] = hh;
            *(ushort4*)&wt_lo[sc][sk0 + j] = ll;
        }
        __syncthreads();

        f32x4 acc[4];
#pragma unroll
        for (int t = 0; t < 4; t++) acc[t] = (f32x4){0.0f, 0.0f, 0.0f, 0.0f};
#pragma unroll
        for (int kc = 0; kc < 4; kc++) {
            int kk = kc * 32 + g * 8;
#pragma unroll
            for (int t = 0; t < 4; t++) {
                bf16x8 bh = *(const bf16x8*)&wt_hi[t * 16 + r][kk];
                bf16x8 bl = *(const bf16x8*)&wt_lo[t * 16 + r][kk];
                acc[t] = __builtin_amdgcn_mfma_f32_16x16x32_bf16(ahi[kc], bh, acc[t], 0, 0, 0);
                acc[t] = __builtin_amdgcn_mfma_f32_16x16x32_bf16(ahi[kc], bl, acc[t], 0, 0, 0);
            }
        }

        size_t orow = (size_t)blockIdx.x * 64 + wv * 16 + g * 4;
#pragma unroll
        for (int t = 0; t < 4; t++) {
            int cc = h * 64 + t * 16 + r;
            float bv = bias[cc];
#pragma unroll
            for (int q = 0; q < 4; q++)
                out[(orow + q) * 128 + cc] = f2bf_rne(acc[t][q] + bv);
        }
    }
}

// ---------------- fused gather 1 (bf16 XL -> bf16 AGG, 4 nodes/wave, unroll-2) ----------------
// AGG = isq[n]*sum(isq[r]*relu(XL[r])) + relu(XL[n]+root)*isq[n]^2
__global__ __launch_bounds__(256) void k_gather1(const unsigned short* __restrict__ XLb,
                                                 unsigned short* __restrict__ AGG,
                                                 const int* __restrict__ adj, const int* __restrict__ ptr,
                                                 const float* __restrict__ isq,
                                                 const float* __restrict__ root) {
    const uint4* XLq = (const uint4*)XLb;    // 16 uint4 per row (128 bf16)
    int tid = threadIdx.x;
    int c = tid & 15;                        // col octet: bf16 cols 8c..8c+7
    int n = blockIdx.x * 16 + (tid >> 4);    // 16 nodes per 256-thread block
    int s = ptr[n], e = ptr[n + 1];
    float4 A0 = {0.0f, 0.0f, 0.0f, 0.0f}, A1 = {0.0f, 0.0f, 0.0f, 0.0f};
    int i = s;
    for (; i + 2 <= e; i += 2) {             // unroll-2: two row loads in flight
        int r0 = adj[i], r1 = adj[i + 1];
        float w0 = isq[r0], w1 = isq[r1];
        uint4 u0 = XLq[(size_t)r0 * 16 + c];
        uint4 u1 = XLq[(size_t)r1 * 16 + c];
        acc8(A0, A1, w0, u0);
        acc8(A0, A1, w1, u1);
    }
    if (i < e) {
        int r0 = adj[i];
        float w0 = isq[r0];
        uint4 u0 = XLq[(size_t)r0 * 16 + c];
        acc8(A0, A1, w0, u0);
    }
    float iq = isq[n];
    float id = iq * iq;
    uint4 su = XLq[(size_t)n * 16 + c];
    float4 rv0 = ((const float4*)root)[2 * c];
    float4 rv1 = ((const float4*)root)[2 * c + 1];
    float o0 = iq * A0.x + fmaxf(bfu2f(su.x)  + rv0.x, 0.0f) * id;
    float o1 = iq * A0.y + fmaxf(bfhi2f(su.x) + rv0.y, 0.0f) * id;
    float o2 = iq * A0.z + fmaxf(bfu2f(su.y)  + rv0.z, 0.0f) * id;
    float o3 = iq * A0.w + fmaxf(bfhi2f(su.y) + rv0.w, 0.0f) * id;
    float o4 = iq * A1.x + fmaxf(bfu2f(su.z)  + rv1.x, 0.0f) * id;
    float o5 = iq * A1.y + fmaxf(bfhi2f(su.z) + rv1.y, 0.0f) * id;
    float o6 = iq * A1.z + fmaxf(bfu2f(su.w)  + rv1.z, 0.0f) * id;
    float o7 = iq * A1.w + fmaxf(bfhi2f(su.w) + rv1.w, 0.0f) * id;
    uint4 ov;
    ov.x = pk2bf(o0, o1);
    ov.y = pk2bf(o2, o3);
    ov.z = pk2bf(o4, o5);
    ov.w = pk2bf(o6, o7);
    ((uint4*)AGG)[(size_t)n * 16 + c] = ov;
}

// ---------------- fused gather 2 (bf16 XL, 4 nodes/wave, 16 lanes/node, unroll-2) ----------------
// gather + self + LN + leaky + residual + out slice; LN reduce across 16 lanes x 8 vals.
__global__ __launch_bounds__(256) void k_gather2(const unsigned short* __restrict__ XLb,
                                                 float* __restrict__ H,
                                                 const int* __restrict__ adj, const int* __restrict__ ptr,
                                                 const float* __restrict__ isq,
                                                 const float* __restrict__ root,
                                                 const float* __restrict__ g, const float* __restrict__ b,
                                                 float* __restrict__ out, int layer_off) {
    const uint4* XLq = (const uint4*)XLb;
    int tid = threadIdx.x;
    int c = tid & 15;
    int n = blockIdx.x * 16 + (tid >> 4);
    int s = ptr[n], e = ptr[n + 1];
    float4 A0 = {0.0f, 0.0f, 0.0f, 0.0f}, A1 = {0.0f, 0.0f, 0.0f, 0.0f};
    int i = s;
    for (; i + 2 <= e; i += 2) {
        int r0 = adj[i], r1 = adj[i + 1];
        float w0 = isq[r0], w1 = isq[r1];
        uint4 u0 = XLq[(size_t)r0 * 16 + c];
        uint4 u1 = XLq[(size_t)r1 * 16 + c];
        acc8(A0, A1, w0, u0);
        acc8(A0, A1, w1, u1);
    }
    if (i < e) {
        int r0 = adj[i];
        float w0 = isq[r0];
        uint4 u0 = XLq[(size_t)r0 * 16 + c];
        acc8(A0, A1, w0, u0);
    }
    float iq = isq[n];
    float id = iq * iq;
    uint4 su = XLq[(size_t)n * 16 + c];
    float4 rv0 = ((const float4*)root)[2 * c];
    float4 rv1 = ((const float4*)root)[2 * c + 1];
    float t0 = iq * A0.x + fmaxf(bfu2f(su.x)  + rv0.x, 0.0f) * id;
    float t1 = iq * A0.y + fmaxf(bfhi2f(su.x) + rv0.y, 0.0f) * id;
    float t2 = iq * A0.z + fmaxf(bfu2f(su.y)  + rv0.z, 0.0f) * id;
    float t3 = iq * A0.w + fmaxf(bfhi2f(su.y) + rv0.w, 0.0f) * id;
    float t4 = iq * A1.x + fmaxf(bfu2f(su.z)  + rv1.x, 0.0f) * id;
    float t5 = iq * A1.y + fmaxf(bfhi2f(su.z) + rv1.y, 0.0f) * id;
    float t6 = iq * A1.z + fmaxf(bfu2f(su.w)  + rv1.z, 0.0f) * id;
    float t7 = iq * A1.w + fmaxf(bfhi2f(su.w) + rv1.w, 0.0f) * id;

    float sm = ((t0 + t1) + (t2 + t3)) + ((t4 + t5) + (t6 + t7));
#pragma unroll
    for (int off = 8; off; off >>= 1) sm += __shfl_xor(sm, off, 16);
    float mu = sm * (1.0f / 128.0f);
    float d0 = t0 - mu, d1 = t1 - mu, d2 = t2 - mu, d3 = t3 - mu;
    float d4 = t4 - mu, d5 = t5 - mu, d6 = t6 - mu, d7 = t7 - mu;
    float q = ((d0 * d0 + d1 * d1) + (d2 * d2 + d3 * d3))
            + ((d4 * d4 + d5 * d5) + (d6 * d6 + d7 * d7));
#pragma unroll
    for (int off = 8; off; off >>= 1) q += __shfl_xor(q, off, 16);
    float rs = rsqrtf(q * (1.0f / 128.0f) + LNEPS);

    float4 gv0 = ((const float4*)g)[2 * c];
    float4 gv1 = ((const float4*)g)[2 * c + 1];
    float4 bv0 = ((const float4*)b)[2 * c];
    float4 bv1 = ((const float4*)b)[2 * c + 1];
    float y0 = leakyf(d0 * rs * gv0.x + bv0.x);
    float y1 = leakyf(d1 * rs * gv0.y + bv0.y);
    float y2 = leakyf(d2 * rs * gv0.z + bv0.z);
    float y3 = leakyf(d3 * rs * gv0.w + bv0.w);
    float y4 = leakyf(d4 * rs * gv1.x + bv1.x);
    float y5 = leakyf(d5 * rs * gv1.y + bv1.y);
    float y6 = leakyf(d6 * rs * gv1.z + bv1.z);
    float y7 = leakyf(d7 * rs * gv1.w + bv1.w);

    float4* h4 = (float4*)H + (size_t)n * 32 + 2 * c;
    float4 hv0 = h4[0];
    float4 hv1 = h4[1];
    float4 o0, o1;
    o0.x = y0 + hv0.x; o0.y = y1 + hv0.y; o0.z = y2 + hv0.z; o0.w = y3 + hv0.w;
    o1.x = y4 + hv1.x; o1.y = y5 + hv1.y; o1.z = y6 + hv1.z; o1.w = y7 + hv1.w;
    h4[0] = o0;
    h4[1] = o1;
    if (n < NI_C) {
        float4* og = (float4*)out + (size_t)n * 128 + (layer_off >> 2) + 2 * c;
        og[0] = o0;
        og[1] = o1;
    }
}

extern "C" void kernel_launch(void* const* d_in, const int* in_sizes, int n_in,
                              void* d_out, int out_size, void* d_ws, size_t ws_size,
                              hipStream_t stream) {
    const float* x         = (const float*)d_in[0];
    const float* enc_w1    = (const float*)d_in[1];
    const float* enc_b1    = (const float*)d_in[2];
    const float* enc_w2    = (const float*)d_in[3];
    const float* enc_b2    = (const float*)d_in[4];
    const float* conv_w    = (const float*)d_in[5];
    const float* conv_b    = (const float*)d_in[6];
    const float* conv_root = (const float*)d_in[7];
    const float* reconv_w    = (const float*)d_in[8];
    const float* reconv_b    = (const float*)d_in[9];
    const float* reconv_root = (const float*)d_in[10];
    const float* ln_g = (const float*)d_in[11];
    const float* ln_b = (const float*)d_in[12];
    const int* ei_nn  = (const int*)d_in[13];
    const int* ei_net = (const int*)d_in[14];
    float* out = (float*)d_out;

    char* ws = (char*)d_ws;
    size_t off = 0;
    const size_t big = (size_t)NN * EMB * sizeof(float);  // 102.4 MB
    float* H  = (float*)(ws + off); off += big;
    unsigned short* XL = (unsigned short*)(ws + off); off += big;  // bf16, half used
    unsigned short* HC = (unsigned short*)(ws + off); off += big;  // bf16 AGG, half used
    float* isq_nn  = (float*)(ws + off); off += (size_t)NN * 4;
    float* isq_net = (float*)(ws + off); off += (size_t)NN * 4;
    // histogram block (contiguous for single memset): cnt_nn, cnt_net, ccol_nn, ccol_net
    int* cnt_nn  = (int*)(ws + off); off += (size_t)NN * 4;   // reused as cur_nn after k_deg
    int* cnt_net = (int*)(ws + off); off += (size_t)NN * 4;   // reused as cur_net
    int* ccol_nn  = (int*)(ws + off); off += (size_t)NN * 4;
    int* ccol_net = (int*)(ws + off); off += (size_t)NN * 4;
    int* ptr_nn  = (int*)(ws + off); off += (size_t)(NN + 1) * 4;
    int* ptr_net = (int*)(ws + off); off += (size_t)(NN + 1) * 4;
    int* adj_nn  = (int*)(ws + off); off += (size_t)EE * 4;
    int* adj_net = (int*)(ws + off); off += (size_t)EE * 4;
    int* bsum_nn  = (int*)(ws + off); off += (size_t)1024 * 4;
    int* bsum_net = (int*)(ws + off); off += (size_t)1024 * 4;

    // ---- CSR + degree build (once per launch, reused by all 3 layers) ----
    hipMemsetAsync(cnt_nn, 0, (size_t)NN * 4 * 4, stream);  // all 4 histograms
    k_hist<<<(EE + 255) / 256, 256, 0, stream>>>(ei_nn, ei_net, cnt_nn, cnt_net, ccol_nn, ccol_net);
    k_deg<<<(NN + 255) / 256, 256, 0, stream>>>(cnt_nn, cnt_net, isq_nn, isq_net);
    k_scan1<<<CH, 256, 0, stream>>>(ccol_nn, ptr_nn, bsum_nn);
    k_scan1<<<CH, 256, 0, stream>>>(ccol_net, ptr_net, bsum_net);
    k_scan2<<<1, 1024, 0, stream>>>(bsum_nn);
    k_scan2<<<1, 1024, 0, stream>>>(bsum_net);
    k_scan3<<<CH, 256, 0, stream>>>(ptr_nn, bsum_nn);
    k_scan3<<<CH, 256, 0, stream>>>(ptr_net, bsum_net);
    hipMemsetAsync(cnt_nn, 0, (size_t)NN * 4 * 2, stream);  // zero fill cursors (reuse cnt)
    k_fill<<<(EE + 255) / 256, 256, 0, stream>>>(ei_nn, ei_net, ptr_nn, ptr_net,
                                                 cnt_nn, cnt_net, adj_nn, adj_net);

    // ---- encoder -> H, out[:,0:128] ----
    k_encoder<<<NN / 64, 256, 0, stream>>>(x, enc_w1, enc_b1, enc_w2, enc_b2, H, out);

    for (int l = 0; l < 3; l++) {
        // GCN 1 (node_net edges): H(fp32) @ W -> XL(bf16); gather -> HC(bf16)
        k_matmul_mfma<<<NN / 64, 256, 0, stream>>>(H, conv_w + (size_t)l * EMB * EMB, conv_b + l * EMB, XL);
        k_gather1<<<NN / 16, 256, 0, stream>>>(XL, HC, adj_nn, ptr_nn, isq_nn, conv_root + l * EMB);

        // GCN 2 (net_node edges): HC(bf16) @ W -> XL(bf16); gather + LN + residual
        k_matmul_mfma_b16<<<NN / 64, 256, 0, stream>>>(HC, reconv_w + (size_t)l * EMB * EMB, reconv_b + l * EMB, XL);
        k_gather2<<<NN / 16, 256, 0, stream>>>(XL, H, adj_net, ptr_net, isq_net, reconv_root + l * EMB,
                                               ln_g + l * EMB, ln_b + l * EMB, out, (l + 1) * EMB);
    }
}